// Round 13
// baseline (270.965 us; speedup 1.0000x reference)
//
#include <hip/hip_runtime.h>
#include <math.h>

// ---------------------------------------------------------------------------
// VQVAE forward. v21: vqdproj cbT-reuse. v20 model: vqdproj (~15 us) is L2-
// traffic-bound -- 2048 blocks x 131 KB cbT re-read = 268 MB (~8 us floor).
// v21: grid 512 = b x piq(16); each block computes 4 SITES per cbT read
// (a[4][4] f64 accums, statically indexed) -> traffic /4. Per-(site,code)
// FMA order, accumulator grouping, compare order, and reduction fold are
// EXACTLY v15's -> idx/z_q/Y bit-identical. Loss: site s by wave s.
// dproj: 512 outputs over 256 threads, identical serial d-loop.
// Everything else unchanged from v20.
// ---------------------------------------------------------------------------

typedef _Float16 f16x8 __attribute__((ext_vector_type(8)));
typedef float f32x4 __attribute__((ext_vector_type(4)));

#define H1N 16777216        // elements in h1 plane; zero tail after
#define YTAIL (2048 * 128)  // zero page in Yh/Yl for OOB shifts

// ---------- prep: A-agg (0..127), W-layout (128..143), cbT (144..151), misc -
__global__ __launch_bounds__(256) void k_prep(const float* __restrict__ w2,
                                              const float* __restrict__ w1,
                                              const float* __restrict__ wp,
                                              const float* __restrict__ wd,
                                              const float* __restrict__ wd1,
                                              const float* __restrict__ cb,
                                              float* __restrict__ w1t,
                                              float* __restrict__ wpT,
                                              float* __restrict__ wdT,
                                              float* __restrict__ cbT,
                                              _Float16* __restrict__ Ah,
                                              _Float16* __restrict__ Al,
                                              _Float16* __restrict__ WS,
                                              _Float16* __restrict__ h1h) {
  int bx = blockIdx.x, tid = threadIdx.x;
  if (bx < 128) {  // ---- A aggregation, block = co, lanes = ci (writes coalesced)
    __shared__ float wrow[1152];
    int co = bx;
    for (int i = tid; i < 1152; i += 256) wrow[i] = wd1[co * 1152 + i];
    __syncthreads();
    if (tid < 128) {
      int ci = tid;
      float w[9];
#pragma unroll
      for (int t = 0; t < 9; t++) w[t] = wrow[ci * 9 + t];
      float rx[3][5];
#pragma unroll
      for (int ky = 0; ky < 3; ky++) {
        float a0 = w[ky * 3 + 0], a1 = w[ky * 3 + 1], a2 = w[ky * 3 + 2];
        rx[ky][0] = a0; rx[ky][1] = a1 + a2; rx[ky][2] = a0 + a1 + a2;
        rx[ky][3] = a0 + a1; rx[ky][4] = a2;
      }
#pragma unroll
      for (int px = 0; px < 5; px++) {
        float s0 = rx[0][px], s1 = rx[1][px], s2 = rx[2][px];
        float ry[5];
        ry[0] = s0; ry[1] = s1 + s2; ry[2] = s0 + s1 + s2; ry[3] = s0 + s1; ry[4] = s2;
#pragma unroll
        for (int py = 0; py < 5; py++) {
          int pq = py * 5 + px;
          float v = ry[py];
          _Float16 h = (_Float16)v;
          int o = (pq * 128 + co) * 128 + ci;
          Ah[o] = h;
          Al[o] = (_Float16)(v - (float)h);
        }
      }
    }
    return;
  }
  if (bx < 144) {  // ---- W layout for conv2 staging: [pl][tap][ci8g][co]x8
    __shared__ float wst[9216];
    int co0 = (bx - 128) * 8;
    for (int i = tid; i < 9216; i += 256) wst[i] = w2[co0 * 1152 + i];
    __syncthreads();
    for (int i = tid; i < 9216; i += 256) {
      int co = i / 1152, r = i - co * 1152;
      int tap = r >> 7, ci = r & 127;
      float v = wst[co * 1152 + ci * 9 + tap];
      _Float16 h = (_Float16)v;
      int og = ((tap * 16 + (ci >> 3)) * 128 + co0 + co) * 8 + (ci & 7);
      WS[og] = h;                                   // pl = 0 (high)
      WS[og + 147456] = (_Float16)(v - (float)h);   // pl = 1 (low); 9*16*128*8
    }
    return;
  }
  if (bx < 152) {  // ---- cbT tile transpose (64 k x 64 d), padded LDS
    __shared__ float cbs[64 * 65];
    int k0 = (bx - 144) * 64;
    for (int i = tid; i < 4096; i += 256) {
      int k = i >> 6, d = i & 63;
      cbs[k * 65 + d] = cb[(k0 + k) * 64 + d];
    }
    __syncthreads();
    for (int i = tid; i < 4096; i += 256) {
      int d = i >> 6, k = i & 63;
      cbT[d * 512 + k0 + k] = cbs[k * 65 + d];
    }
    return;
  }
  // ---- misc small transposes + h1 zero tail (writes lane-contiguous)
  for (int i = tid; i < 3456; i += 256) {  // w1t[t][co] = w1[co][t]
    int co = i & 127, t = i >> 7;
    w1t[t * 128 + co] = w1[co * 27 + t];
  }
  for (int i = tid; i < 8192; i += 256) {  // wpT[k][d] = wp[d][k]
    int d = i & 63, k = i >> 6;
    wpT[k * 64 + d] = wp[d * 128 + k];
  }
  for (int i = tid; i < 8192; i += 256) {  // wdT[d][co] = wd[co][d]
    int co = i & 127, d = i >> 7;
    wdT[d * 128 + co] = wd[co * 64 + d];
  }
  if (tid < 64) h1h[H1N + tid] = (_Float16)0.f;
}

// ---------- conv1: (32,3,128,128) -> h1 f16 [g][b][oh][ow][8ci] -------------
__global__ __launch_bounds__(256) void k_conv1(const float* __restrict__ x,
                                               const float* __restrict__ w1t,
                                               const float* __restrict__ b1,
                                               _Float16* __restrict__ h1h) {
  __shared__ float E[3][9][68];
  __shared__ float O[3][9][68];
  int co_t = blockIdx.x, oh_t = blockIdx.y, b = blockIdx.z;
  int oh0 = oh_t * 4;
  int tid = threadIdx.x;
  int wv = __builtin_amdgcn_readfirstlane(tid >> 6);
  int l = tid & 63;
  int coB = co_t * 32 + wv * 8;

  for (int idx = tid; idx < 1728; idx += 256) {
    int p = idx & 63, r = idx >> 6;
    int ci = r / 9, lr = r - ci * 9;
    int ih = 2 * oh0 - 1 + lr;
    float2 v = make_float2(0.f, 0.f);
    if ((unsigned)ih < 128u)
      v = *(const float2*)&x[((b * 3 + ci) * 128 + ih) * 128 + 2 * p];
    E[ci][lr][p] = v.x;
    O[ci][lr][p + 1] = v.y;
  }
  if (tid < 27) {
    int ci = tid / 9, lr = tid - ci * 9;
    O[ci][lr][0] = 0.f;
  }
  __syncthreads();

  int ohl = l >> 4, ow0 = (l & 15) * 4;
  int oh = oh0 + ohl;
  float4 acc[8];
#pragma unroll
  for (int q = 0; q < 8; q++) {
    float bv = b1[coB + q];
    acc[q] = make_float4(bv, bv, bv, bv);
  }
#pragma unroll
  for (int ci = 0; ci < 3; ci++) {
#pragma unroll
    for (int ky = 0; ky < 3; ky++) {
      int lr = 2 * ohl + ky;
      float4 ev = *(float4*)&E[ci][lr][ow0];
      float4 od = *(float4*)&O[ci][lr][ow0];
      float o4 = O[ci][lr][ow0 + 4];
      const float* wr = w1t + (ci * 9 + ky * 3) * 128 + coB;
#pragma unroll
      for (int q = 0; q < 8; q++) {
        float wa = wr[q], wb = wr[128 + q], wc = wr[256 + q];
        acc[q].x = fmaf(wa, od.x, acc[q].x);
        acc[q].x = fmaf(wb, ev.x, acc[q].x);
        acc[q].x = fmaf(wc, od.y, acc[q].x);
        acc[q].y = fmaf(wa, od.y, acc[q].y);
        acc[q].y = fmaf(wb, ev.y, acc[q].y);
        acc[q].y = fmaf(wc, od.z, acc[q].y);
        acc[q].z = fmaf(wa, od.z, acc[q].z);
        acc[q].z = fmaf(wb, ev.z, acc[q].z);
        acc[q].z = fmaf(wc, od.w, acc[q].z);
        acc[q].w = fmaf(wa, od.w, acc[q].w);
        acc[q].w = fmaf(wb, ev.w, acc[q].w);
        acc[q].w = fmaf(wc, o4,   acc[q].w);
      }
    }
  }
  int g = coB >> 3;
  int pbase = ((g * 32 + b) * 64 + oh) * 64;
#pragma unroll
  for (int oi = 0; oi < 4; oi++) {
    f16x8 hv;
#pragma unroll
    for (int q = 0; q < 8; q++)
      hv[q] = (_Float16)fmaxf(((const float*)&acc[q])[oi], 0.f);
    *(f16x8*)&h1h[(pbase + ow0 + oi) * 8] = hv;
  }
}

// ---------- conv2: fat-step all-LDS compute + fused 4x4 mean-pool ----------
#define C2_ACHUNK 4420                          // 4*17*65
#define C2_WCHUNK 4680
#define C2_WOFF (C2_ACHUNK * 8)                 // f16 offset of weight region
#define C2_LDSB ((C2_ACHUNK + C2_WCHUNK) * 16)  // 145600 bytes
#define C2_STEP 4194304                         // h1 advance per +32ci step
#define C2_WADV 4096                            // WS f16 advance per step

__global__ __launch_bounds__(512, 2) void k_conv2(const _Float16* __restrict__ h1h,
                                                  const _Float16* __restrict__ WS,
                                                  const float* __restrict__ b2,
                                                  float* __restrict__ h2p) {
  extern __shared__ _Float16 L[];
  int bx = blockIdx.x;
  int cohalf = bx & 1;
  int bq = bx >> 1;
  int b = bq >> 2, ohq = bq & 3;
  int oh0 = ohq * 8;
  int tid = threadIdx.x;
  int w = tid >> 6, l = tid & 63;
  int cw = w & 1, rw = w >> 1;
  int ln = l & 15, quad = l >> 4;

  // ---- act staging descriptors: 9 chunks/thread (tail tid<324) ----
  int cursA[9];
  int advA[9];
#pragma unroll
  for (int k = 0; k < 9; k++) {
    int c = (k < 8) ? (tid + k * 512) : (4096 + tid);
    if (c < C2_ACHUNK) {
      int q = c / 65, rem = c - q * 65;
      int ph = rem >= 33;
      int u = ph ? rem - 33 : rem;
      int r = q % 17, g = q / 17;
      int iw = ph ? 2 * u : 2 * u - 1;
      int ih = 2 * oh0 - 1 + r;
      bool ok = (ih >= 0) && (iw >= 0) && (iw < 64);
      cursA[k] = ok ? ((g * 32 + b) * 64 + ih) * 512 + iw * 8 : H1N;
      advA[k] = ok ? C2_STEP : 0;
    } else {
      cursA[k] = H1N;
      advA[k] = 0;
    }
  }
  // ---- weight staging descriptors: 10 chunks/thread (tail tid<72) ----
  int cursW[10];
#pragma unroll
  for (int k = 0; k < 10; k++) {
    int c = (k < 9) ? (tid + k * 512) : (4608 + tid);
    if (c < C2_WCHUNK) {
      int q65 = c / 65, u = c - q65 * 65;
      if (u > 63) u = 63;  // pad slot: stage harmless duplicate
      int pl = q65 >= 36;
      int r36 = q65 - pl * 36;
      int t = r36 >> 2, ci8 = r36 & 3;
      cursW[k] = ((pl * 9 + t) * 16 + ci8) * 1024 + (cohalf * 64 + u) * 8;
    } else {
      cursW[k] = 0;
    }
  }

  f32x4 acc[2][4] = {};  // [cs][s]
  for (int step = 0; step < 4; step++) {
    if (step) __syncthreads();  // prior compute done reading L
    // ---- stage acts(step) ----
#pragma unroll
    for (int k = 0; k < 8; k++) {
      __builtin_amdgcn_global_load_lds(
          (const __attribute__((address_space(1))) void*)(h1h + cursA[k]),
          (__attribute__((address_space(3))) void*)&L[(tid + k * 512) * 8],
          16, 0, 0);
      cursA[k] += advA[k];
    }
    if (tid < 324)
      __builtin_amdgcn_global_load_lds(
          (const __attribute__((address_space(1))) void*)(h1h + cursA[8]),
          (__attribute__((address_space(3))) void*)&L[(4096 + tid) * 8],
          16, 0, 0);
    cursA[8] += advA[8];
    // ---- stage weights(step) ----
#pragma unroll
    for (int k = 0; k < 9; k++) {
      __builtin_amdgcn_global_load_lds(
          (const __attribute__((address_space(1))) void*)(WS + cursW[k]),
          (__attribute__((address_space(3))) void*)&L[C2_WOFF +
                                                     (tid + k * 512) * 8],
          16, 0, 0);
      cursW[k] += C2_WADV;
    }
    if (tid < 72)
      __builtin_amdgcn_global_load_lds(
          (const __attribute__((address_space(1))) void*)(WS + cursW[9]),
          (__attribute__((address_space(3))) void*)&L[C2_WOFF +
                                                     (4608 + tid) * 8],
          16, 0, 0);
    cursW[9] += C2_WADV;
    __syncthreads();  // drain: acts + weights resident

    // ---- compute: pure LDS + MFMA (144 MFMA/wave/step) ----
#pragma unroll
    for (int ky = 0; ky < 3; ky++) {
#pragma unroll
      for (int kx = 0; kx < 3; kx++) {
        int t = ky * 3 + kx;
        int wb = (t * 4 + quad) * 65 + cw * 32 + ln;
        f16x8 Ah0 = *(const f16x8*)&L[C2_WOFF + wb * 8];
        f16x8 Ah1 = *(const f16x8*)&L[C2_WOFF + (wb + 16) * 8];
        f16x8 Al0 = *(const f16x8*)&L[C2_WOFF + (wb + 2340) * 8];
        f16x8 Al1 = *(const f16x8*)&L[C2_WOFF + (wb + 2356) * 8];
#pragma unroll
        for (int s = 0; s < 4; s++) {
          int owl = (s & 1) * 16 + ln;
          int r = 4 * rw + 2 * (s >> 1) + ky;
          int abase = (quad * 17 + r) * 65;
          int uoff = (kx == 1) ? (33 + owl) : (owl + (kx == 2));
          f16x8 Bh = *(const f16x8*)&L[(abase + uoff) * 8];
          acc[0][s] = __builtin_amdgcn_mfma_f32_16x16x32_f16(Al0, Bh, acc[0][s], 0, 0, 0);
          acc[0][s] = __builtin_amdgcn_mfma_f32_16x16x32_f16(Ah0, Bh, acc[0][s], 0, 0, 0);
          acc[1][s] = __builtin_amdgcn_mfma_f32_16x16x32_f16(Al1, Bh, acc[1][s], 0, 0, 0);
          acc[1][s] = __builtin_amdgcn_mfma_f32_16x16x32_f16(Ah1, Bh, acc[1][s], 0, 0, 0);
        }
      }
    }
  }
  // ---- epilogue: fused 4x4 mean-pool ----
  __syncthreads();  // all waves done reading L; reuse act region as h2s
  float* h2s = (float*)L;  // [64co][8row][32col] = 65536 B < 70720 B
#pragma unroll
  for (int cs = 0; cs < 2; cs++)
#pragma unroll
    for (int s = 0; s < 4; s++) {
      int row = 2 * rw + (s >> 1);
      int col = (s & 1) * 16 + ln;
#pragma unroll
      for (int r2 = 0; r2 < 4; r2++) {
        int co64 = cw * 32 + cs * 16 + quad * 4 + r2;
        int co = cohalf * 64 + co64;
        h2s[(co64 * 8 + row) * 32 + col] = fmaxf(acc[cs][s][r2] + b2[co], 0.f);
      }
    }
  __syncthreads();
  // 1024 pool cells (64co x 2pr x 8pc); v19 poolproj's exact add order
  for (int c = tid; c < 1024; c += 512) {
    int co64 = c >> 4, rem = c & 15;
    int pr = rem >> 3, pc = rem & 7;
    const float* base = &h2s[(co64 * 8 + pr * 4) * 32 + pc * 4];
    float s = 0.f;
#pragma unroll
    for (int rr = 0; rr < 4; rr++) {
      s += base[rr * 32 + 0];
      s += base[rr * 32 + 1];
      s += base[rr * 32 + 2];
      s += base[rr * 32 + 3];
    }
    h2p[((b * 128 + cohalf * 64 + co64) * 8 + (2 * ohq + pr)) * 8 + pc] =
        s * 0.0625f;
  }
}

// ---------- proj(1x1,128->64) on pooled input; grid 128 (b x quarter) -------
__global__ __launch_bounds__(256) void k_poolproj(const float* __restrict__ h2p,
                                                  const float* __restrict__ wpT,
                                                  const float* __restrict__ pb,
                                                  float* __restrict__ z_e_out,
                                                  float* __restrict__ lossacc) {
  __shared__ float hp[128][16];
  __shared__ float Ws[128][64];
  int bx = blockIdx.x, tid = threadIdx.x;
  int b = bx >> 2, quarter = bx & 3;
  if (bx == 0 && tid == 0) lossacc[0] = 0.f;
  for (int i = tid; i < 8192; i += 256) Ws[i >> 6][i & 63] = wpT[i];
  for (int i = tid; i < 2048; i += 256) {
    int ci = i >> 4, pl = i & 15;
    hp[ci][pl] = h2p[(b * 128 + ci) * 64 + quarter * 16 + pl];
  }
  __syncthreads();
  int d = tid >> 2, s0 = (tid & 3) * 4;
  float4 acc = make_float4(0.f, 0.f, 0.f, 0.f);
  for (int k = 0; k < 128; k++) {
    float a = Ws[k][d];
    float4 h = *(float4*)&hp[k][s0];
    acc.x = fmaf(a, h.x, acc.x);
    acc.y = fmaf(a, h.y, acc.y);
    acc.z = fmaf(a, h.z, acc.z);
    acc.w = fmaf(a, h.w, acc.w);
  }
  float bv = pb[d];
  float4 r4 = make_float4(acc.x + bv, acc.y + bv, acc.z + bv, acc.w + bv);
  *(float4*)&z_e_out[(b * 64 + d) * 64 + quarter * 16 + s0] = r4;
}

// ---------- VQ argmin + loss + dproj; grid 512 x 256: 4 sites/block ---------
// Block (b, piq) handles sites pi0..pi0+3 (pi0 = piq*4). Wave w owns codes
// [w*128, +128), 2/lane; cbT values loaded ONCE per d-step and reused across
// 4 sites (a[4][4] f64, statically indexed). Per-(site,code) FMA order,
// accumulator grouping, compare order, wave shuffle reduce, and ascending
// 4-way fold are exactly v15's -> idx/z_q/Y bit-identical.
__global__ __launch_bounds__(256) void k_vqdproj(const float* __restrict__ z_e,
                                                 const float* __restrict__ cbT,
                                                 const float* __restrict__ cb,
                                                 const float* __restrict__ wdT,
                                                 const float* __restrict__ db,
                                                 float* __restrict__ idx_f,
                                                 _Float16* __restrict__ Yh,
                                                 _Float16* __restrict__ Yl,
                                                 float* __restrict__ loss_acc) {
  __shared__ float zs[4][64];
  __shared__ float zqv[4][64];
  __shared__ double wbst[4][4];  // [site][wave]
  __shared__ int wbi[4][4];
  int bx = blockIdx.x, tid = threadIdx.x;
  int b = bx >> 4, piq = bx & 15;
  int pi0 = piq * 4;
  for (int i = tid; i < 256; i += 256) {
    int site = i & 3, d = i >> 2;
    zs[site][d] = z_e[(b * 64 + d) * 64 + pi0 + site];
  }
  if (bx == 0 && tid < 64) {  // zero tail page for shifted reads in k_dec
    Yh[YTAIL + tid] = (_Float16)0.f;
    Yh[YTAIL + 64 + tid] = (_Float16)0.f;
    Yl[YTAIL + tid] = (_Float16)0.f;
    Yl[YTAIL + 64 + tid] = (_Float16)0.f;
  }
  __syncthreads();
  int w = tid >> 6, lane = tid & 63;
  double best[4];
  int bi[4];
#pragma unroll
  for (int s2 = 0; s2 < 4; s2++) { best[s2] = 1e300; bi[s2] = 0; }
#pragma unroll
  for (int j = 0; j < 2; j++) {
    int k = w * 128 + j * 64 + lane;
    double a[4][4];
#pragma unroll
    for (int s2 = 0; s2 < 4; s2++)
#pragma unroll
      for (int q = 0; q < 4; q++) a[s2][q] = 0.0;
    for (int d = 0; d < 64; d += 4) {
      double c0 = (double)cbT[d * 512 + k];
      double c1 = (double)cbT[(d + 1) * 512 + k];
      double c2 = (double)cbT[(d + 2) * 512 + k];
      double c3 = (double)cbT[(d + 3) * 512 + k];
#pragma unroll
      for (int s2 = 0; s2 < 4; s2++) {
        double f0 = (double)zs[s2][d] - c0;
        double f1 = (double)zs[s2][d + 1] - c1;
        double f2 = (double)zs[s2][d + 2] - c2;
        double f3 = (double)zs[s2][d + 3] - c3;
        a[s2][0] = fma(f0, f0, a[s2][0]);
        a[s2][1] = fma(f1, f1, a[s2][1]);
        a[s2][2] = fma(f2, f2, a[s2][2]);
        a[s2][3] = fma(f3, f3, a[s2][3]);
      }
    }
#pragma unroll
    for (int s2 = 0; s2 < 4; s2++) {
      double accv = (a[s2][0] + a[s2][1]) + (a[s2][2] + a[s2][3]);
      if (accv < best[s2]) { best[s2] = accv; bi[s2] = k; }
    }
  }
#pragma unroll
  for (int s2 = 0; s2 < 4; s2++) {
    double bb = best[s2];
    int bix = bi[s2];
    for (int m = 1; m < 64; m <<= 1) {
      double ob = __shfl_xor(bb, m, 64);
      int oi = __shfl_xor(bix, m, 64);
      if (ob < bb || (ob == bb && oi < bix)) { bb = ob; bix = oi; }
    }
    if (lane == 0) { wbst[s2][w] = bb; wbi[s2][w] = bix; }
  }
  __syncthreads();
  {  // site s2 = w handled by wave w: fold ascending, loss, zq stage
    int s2 = w;
    double bb = wbst[s2][0];
    int bix = wbi[s2][0];
#pragma unroll
    for (int q = 1; q < 4; q++) {
      double ob = wbst[s2][q];
      int oi = wbi[s2][q];
      if (ob < bb || (ob == bb && oi < bix)) { bb = ob; bix = oi; }
    }
    int n = b * 64 + pi0 + s2;
    float zq_l = cb[bix * 64 + lane];
    float e = zq_l - zs[s2][lane];
    float sq = e * e;
    for (int m = 1; m < 64; m <<= 1) sq += __shfl_xor(sq, m, 64);
    if (lane == 0) {
      idx_f[n] = (float)bix;
      atomicAdd(loss_acc, sq);
    }
    zqv[s2][lane] = zq_l;
  }
  __syncthreads();
  for (int i = tid; i < 512; i += 256) {  // dproj: (site, co) per output
    int s2 = i >> 7, co = i & 127;
    int n = b * 64 + pi0 + s2;
    float a = db[co];
#pragma unroll 4
    for (int d = 0; d < 64; d++) a = fmaf(wdT[d * 128 + co], zqv[s2][d], a);
    float y = fmaxf(a, 0.f);
    _Float16 h = (_Float16)y;
    Yh[n * 128 + co] = h;
    Yl[n * 128 + co] = (_Float16)(y - (float)h);
  }
}

// ---------- dec: per-CLASS accumulated f16-split MFMA -> Tb[9][2048][128] ---
__global__ __launch_bounds__(256) void k_dec(const _Float16* __restrict__ Yh,
                                             const _Float16* __restrict__ Yl,
                                             const _Float16* __restrict__ Ah,
                                             const _Float16* __restrict__ Al,
                                             const float* __restrict__ bc1,
                                             float* __restrict__ Tb) {
  int bxx = blockIdx.x;
  int cls = bxx >> 6, n_t = bxx & 63;
  int rc = cls / 3, c3 = cls - rc * 3;
  const int rset[3][2] = {{0, 1}, {2, 2}, {3, 4}};
  const int rcnt[3] = {2, 1, 2};
  int w = threadIdx.x >> 6, l = threadIdx.x & 63;
  int ln = l & 15, quad = l >> 4;
  int coW = w * 32;
  int nB = n_t * 32;
  int kq = quad * 8;
  f32x4 acc[2][2] = {};
  for (int iy = 0; iy < rcnt[rc]; iy++) {
    int py = rset[rc][iy];
    int dy = (py == 0) ? -1 : ((py == 4) ? 1 : 0);
    for (int ix = 0; ix < rcnt[c3]; ix++) {
      int px = rset[c3][ix];
      int dx = (px == 0) ? -1 : ((px == 4) ? 1 : 0);
      int pq = py * 5 + px;
      int src[2];
#pragma unroll
      for (int s = 0; s < 2; s++) {
        int n = nB + s * 16 + ln;
        int bb = n >> 6, s6 = n & 63;
        int sy = (s6 >> 3) + dy, sx = (s6 & 7) + dx;
        bool ok = ((unsigned)sy < 8u) && ((unsigned)sx < 8u);
        src[s] = ok ? ((bb * 64 + sy * 8 + sx) * 128) : YTAIL;
      }
#pragma unroll 2
      for (int ci0 = 0; ci0 < 128; ci0 += 32) {
        const int wbase = (pq * 128 + coW + ln) * 128 + ci0 + kq;
        f16x8 Ah0 = *(const f16x8*)&Ah[wbase];
        f16x8 Al0 = *(const f16x8*)&Al[wbase];
        f16x8 Ah1 = *(const f16x8*)&Ah[wbase + 2048];
        f16x8 Al1 = *(const f16x8*)&Al[wbase + 2048];
        f16x8 Bh[2], Bl[2];
#pragma unroll
        for (int s = 0; s < 2; s++) {
          Bh[s] = *(const f16x8*)&Yh[src[s] + ci0 + kq];
          Bl[s] = *(const f16x8*)&Yl[src[s] + ci0 + kq];
        }
#pragma unroll
        for (int cs = 0; cs < 2; cs++) {
          f16x8 ah = cs ? Ah1 : Ah0;
          f16x8 al = cs ? Al1 : Al0;
#pragma unroll
          for (int s = 0; s < 2; s++) {
            acc[cs][s] = __builtin_amdgcn_mfma_f32_16x16x32_f16(al, Bh[s], acc[cs][s], 0, 0, 0);
            acc[cs][s] = __builtin_amdgcn_mfma_f32_16x16x32_f16(ah, Bl[s], acc[cs][s], 0, 0, 0);
            acc[cs][s] = __builtin_amdgcn_mfma_f32_16x16x32_f16(ah, Bh[s], acc[cs][s], 0, 0, 0);
          }
        }
      }
    }
  }
  // epilogue: bc1 + relu, write Tb[cls][site][co]
#pragma unroll
  for (int cs = 0; cs < 2; cs++)
#pragma unroll
    for (int s = 0; s < 2; s++) {
      int site = nB + s * 16 + ln;
      int co0 = coW + cs * 16 + quad * 4;
      float4 bv = *(const float4*)&bc1[co0];
      float4 g = make_float4(fmaxf(acc[cs][s][0] + bv.x, 0.f),
                             fmaxf(acc[cs][s][1] + bv.y, 0.f),
                             fmaxf(acc[cs][s][2] + bv.z, 0.f),
                             fmaxf(acc[cs][s][3] + bv.w, 0.f));
      *(float4*)&Tb[(cls * 2048 + site) * 128 + co0] = g;
    }
}

// ---------- out: read Tb, 1x1 conv to 3ch, splat ----------------------------
__global__ __launch_bounds__(256) void k_out(const float* __restrict__ TbG,
                                             const float* __restrict__ w3,
                                             const float* __restrict__ b3,
                                             float* __restrict__ xhat,
                                             const float* __restrict__ loss_acc,
                                             float* __restrict__ out_loss) {
  __shared__ float Tb[9][128];
  __shared__ float part[9][3][8];
  __shared__ float vals[9][3];
  int bj = blockIdx.x, bi = blockIdx.y, b = blockIdx.z;
  int s = bi * 8 + bj;
  int n = b * 64 + s;
  int tid = threadIdx.x;
  if (bj == 0 && bi == 0 && b == 0 && tid == 0)
    out_loss[0] = loss_acc[0] * 1.25f / 131072.0f;
  for (int i = tid; i < 1152; i += 256) {
    int cls = i >> 7, co = i & 127;
    Tb[cls][co] = TbG[(cls * 2048 + n) * 128 + co];
  }
  __syncthreads();
  if (tid < 216) {
    int cls = tid / 24, rem = tid - cls * 24;
    int cc = rem >> 3, seg = rem & 7;
    float ss = 0.f;
#pragma unroll
    for (int d = 0; d < 16; d++) ss = fmaf(w3[cc * 128 + seg * 16 + d], Tb[cls][seg * 16 + d], ss);
    part[cls][cc][seg] = ss;
  }
  __syncthreads();
  if (tid < 27) {
    int cls = tid / 3, cc = tid - cls * 3;
    float ss = b3[cc];
#pragma unroll
    for (int seg = 0; seg < 8; seg++) ss += part[cls][cc][seg];
    vals[cls][cc] = ss;
  }
  __syncthreads();
  for (int i = tid; i < 768; i += 256) {
    int cc = i >> 8, p = i & 255;
    int ry = p >> 4, rx = p & 15;
    int rcls = (ry == 0) ? 0 : ((ry == 15) ? 2 : 1);
    int ccls = (rx == 0) ? 0 : ((rx == 15) ? 2 : 1);
    xhat[((b * 3 + cc) * 128 + bi * 16 + ry) * 128 + bj * 16 + rx] =
        vals[rcls * 3 + ccls][cc];
  }
}

extern "C" void kernel_launch(void* const* d_in, const int* in_sizes, int n_in,
                              void* d_out, int out_size, void* d_ws, size_t ws_size,
                              hipStream_t stream) {
  const float* x   = (const float*)d_in[0];
  const float* w1  = (const float*)d_in[1];
  const float* b1  = (const float*)d_in[2];
  const float* w2  = (const float*)d_in[3];
  const float* b2  = (const float*)d_in[4];
  const float* wp  = (const float*)d_in[5];
  const float* pb  = (const float*)d_in[6];
  const float* cb  = (const float*)d_in[7];
  const float* wd  = (const float*)d_in[8];
  const float* db  = (const float*)d_in[9];
  const float* wc1 = (const float*)d_in[10];
  const float* bc1 = (const float*)d_in[11];
  const float* wc2 = (const float*)d_in[12];
  const float* bc2 = (const float*)d_in[13];
  float* out = (float*)d_out;
  float* ws  = (float*)d_ws;

  // workspace (float offsets):
  _Float16* h1h = (_Float16*)(ws);             // [0, 8388640) f16 plane (+tail)
  float* h2p    = ws + 16777280;               // 262144 (pooled)
  _Float16* WS  = (_Float16*)(ws + 20971584);  // 147456 fl (294912 f16)
  float* w1t    = ws + 21119040;               // 3456
  float* wpT    = ws + 21122496;               // 8192
  float* wdT    = ws + 21130688;               // 8192
  float* cbT    = ws + 21138880;               // 32768
  _Float16* Ahd = (_Float16*)(ws + 21171648);  // 204800 fl
  _Float16* Ald = (_Float16*)(ws + 21376448);  // 204800 fl -> end 21581248
  // overlays inside dead h1h region (valid after conv2):
  float* Tb      = ws;                         // [0, 2359296) 9*2048*128
  _Float16* Yh   = (_Float16*)(ws + 6553600);  // 131136 fl (2049*128 f16)
  _Float16* Yl   = (_Float16*)(ws + 6684736);  // 131136 fl
  float* lossacc = ws + 6815872;               // 1

  float* o_xhat = out;
  float* o_idx  = out + 1572864;
  float* o_loss = out + 1574912;
  float* o_ze   = out + 1574913;

  static bool s_attr_done = false;
  if (!s_attr_done) {
    (void)hipFuncSetAttribute((const void*)k_conv2,
                              hipFuncAttributeMaxDynamicSharedMemorySize, C2_LDSB);
    s_attr_done = true;
  }

  k_prep<<<dim3(153), 256, 0, stream>>>(w2, w1, wp, wd, wc1, cb,
                                        w1t, wpT, wdT, cbT, Ahd, Ald, WS, h1h);
  k_conv1<<<dim3(4, 16, 32), 256, 0, stream>>>(x, w1t, b1, h1h);
  k_conv2<<<dim3(256), 512, C2_LDSB, stream>>>(h1h, WS, b2, h2p);
  k_poolproj<<<dim3(128), 256, 0, stream>>>(h2p, wpT, pb, o_ze, lossacc);
  k_vqdproj<<<dim3(512), 256, 0, stream>>>(o_ze, cbT, cb, wdT, db, o_idx, Yh, Yl, lossacc);
  k_dec<<<dim3(576), 256, 0, stream>>>(Yh, Yl, Ahd, Ald, bc1, Tb);
  k_out<<<dim3(8, 8, 32), 256, 0, stream>>>(Tb, wc2, bc2, o_xhat, lossacc, o_loss);
}

// Round 14
// 234.132 us; speedup vs baseline: 1.1573x; 1.1573x over previous
//
#include <hip/hip_runtime.h>
#include <math.h>

// ---------------------------------------------------------------------------
// VQVAE forward. v22: v21's vqdproj spill fixed. v21 counters: VGPR=256,
// WRITE_SIZE 58 MB (scratch) -- the bare d-loop (trip 16) got fully
// unrolled, hoisting all 64 cbT f64 loads -> ~160 live VGPRs -> spill.
// v22 pins #pragma unroll 1 on the j- and d-loops (FMA order unchanged ->
// outputs still bit-identical to v15). cbT-reuse theory (L2 traffic /4)
// now actually gets tested. Everything else unchanged from v21/v20.
// ---------------------------------------------------------------------------

typedef _Float16 f16x8 __attribute__((ext_vector_type(8)));
typedef float f32x4 __attribute__((ext_vector_type(4)));

#define H1N 16777216        // elements in h1 plane; zero tail after
#define YTAIL (2048 * 128)  // zero page in Yh/Yl for OOB shifts

// ---------- prep: A-agg (0..127), W-layout (128..143), cbT (144..151), misc -
__global__ __launch_bounds__(256) void k_prep(const float* __restrict__ w2,
                                              const float* __restrict__ w1,
                                              const float* __restrict__ wp,
                                              const float* __restrict__ wd,
                                              const float* __restrict__ wd1,
                                              const float* __restrict__ cb,
                                              float* __restrict__ w1t,
                                              float* __restrict__ wpT,
                                              float* __restrict__ wdT,
                                              float* __restrict__ cbT,
                                              _Float16* __restrict__ Ah,
                                              _Float16* __restrict__ Al,
                                              _Float16* __restrict__ WS,
                                              _Float16* __restrict__ h1h) {
  int bx = blockIdx.x, tid = threadIdx.x;
  if (bx < 128) {  // ---- A aggregation, block = co, lanes = ci (writes coalesced)
    __shared__ float wrow[1152];
    int co = bx;
    for (int i = tid; i < 1152; i += 256) wrow[i] = wd1[co * 1152 + i];
    __syncthreads();
    if (tid < 128) {
      int ci = tid;
      float w[9];
#pragma unroll
      for (int t = 0; t < 9; t++) w[t] = wrow[ci * 9 + t];
      float rx[3][5];
#pragma unroll
      for (int ky = 0; ky < 3; ky++) {
        float a0 = w[ky * 3 + 0], a1 = w[ky * 3 + 1], a2 = w[ky * 3 + 2];
        rx[ky][0] = a0; rx[ky][1] = a1 + a2; rx[ky][2] = a0 + a1 + a2;
        rx[ky][3] = a0 + a1; rx[ky][4] = a2;
      }
#pragma unroll
      for (int px = 0; px < 5; px++) {
        float s0 = rx[0][px], s1 = rx[1][px], s2 = rx[2][px];
        float ry[5];
        ry[0] = s0; ry[1] = s1 + s2; ry[2] = s0 + s1 + s2; ry[3] = s0 + s1; ry[4] = s2;
#pragma unroll
        for (int py = 0; py < 5; py++) {
          int pq = py * 5 + px;
          float v = ry[py];
          _Float16 h = (_Float16)v;
          int o = (pq * 128 + co) * 128 + ci;
          Ah[o] = h;
          Al[o] = (_Float16)(v - (float)h);
        }
      }
    }
    return;
  }
  if (bx < 144) {  // ---- W layout for conv2 staging: [pl][tap][ci8g][co]x8
    __shared__ float wst[9216];
    int co0 = (bx - 128) * 8;
    for (int i = tid; i < 9216; i += 256) wst[i] = w2[co0 * 1152 + i];
    __syncthreads();
    for (int i = tid; i < 9216; i += 256) {
      int co = i / 1152, r = i - co * 1152;
      int tap = r >> 7, ci = r & 127;
      float v = wst[co * 1152 + ci * 9 + tap];
      _Float16 h = (_Float16)v;
      int og = ((tap * 16 + (ci >> 3)) * 128 + co0 + co) * 8 + (ci & 7);
      WS[og] = h;                                   // pl = 0 (high)
      WS[og + 147456] = (_Float16)(v - (float)h);   // pl = 1 (low); 9*16*128*8
    }
    return;
  }
  if (bx < 152) {  // ---- cbT tile transpose (64 k x 64 d), padded LDS
    __shared__ float cbs[64 * 65];
    int k0 = (bx - 144) * 64;
    for (int i = tid; i < 4096; i += 256) {
      int k = i >> 6, d = i & 63;
      cbs[k * 65 + d] = cb[(k0 + k) * 64 + d];
    }
    __syncthreads();
    for (int i = tid; i < 4096; i += 256) {
      int d = i >> 6, k = i & 63;
      cbT[d * 512 + k0 + k] = cbs[k * 65 + d];
    }
    return;
  }
  // ---- misc small transposes + h1 zero tail (writes lane-contiguous)
  for (int i = tid; i < 3456; i += 256) {  // w1t[t][co] = w1[co][t]
    int co = i & 127, t = i >> 7;
    w1t[t * 128 + co] = w1[co * 27 + t];
  }
  for (int i = tid; i < 8192; i += 256) {  // wpT[k][d] = wp[d][k]
    int d = i & 63, k = i >> 6;
    wpT[k * 64 + d] = wp[d * 128 + k];
  }
  for (int i = tid; i < 8192; i += 256) {  // wdT[d][co] = wd[co][d]
    int co = i & 127, d = i >> 7;
    wdT[d * 128 + co] = wd[co * 64 + d];
  }
  if (tid < 64) h1h[H1N + tid] = (_Float16)0.f;
}

// ---------- conv1: (32,3,128,128) -> h1 f16 [g][b][oh][ow][8ci] -------------
__global__ __launch_bounds__(256) void k_conv1(const float* __restrict__ x,
                                               const float* __restrict__ w1t,
                                               const float* __restrict__ b1,
                                               _Float16* __restrict__ h1h) {
  __shared__ float E[3][9][68];
  __shared__ float O[3][9][68];
  int co_t = blockIdx.x, oh_t = blockIdx.y, b = blockIdx.z;
  int oh0 = oh_t * 4;
  int tid = threadIdx.x;
  int wv = __builtin_amdgcn_readfirstlane(tid >> 6);
  int l = tid & 63;
  int coB = co_t * 32 + wv * 8;

  for (int idx = tid; idx < 1728; idx += 256) {
    int p = idx & 63, r = idx >> 6;
    int ci = r / 9, lr = r - ci * 9;
    int ih = 2 * oh0 - 1 + lr;
    float2 v = make_float2(0.f, 0.f);
    if ((unsigned)ih < 128u)
      v = *(const float2*)&x[((b * 3 + ci) * 128 + ih) * 128 + 2 * p];
    E[ci][lr][p] = v.x;
    O[ci][lr][p + 1] = v.y;
  }
  if (tid < 27) {
    int ci = tid / 9, lr = tid - ci * 9;
    O[ci][lr][0] = 0.f;
  }
  __syncthreads();

  int ohl = l >> 4, ow0 = (l & 15) * 4;
  int oh = oh0 + ohl;
  float4 acc[8];
#pragma unroll
  for (int q = 0; q < 8; q++) {
    float bv = b1[coB + q];
    acc[q] = make_float4(bv, bv, bv, bv);
  }
#pragma unroll
  for (int ci = 0; ci < 3; ci++) {
#pragma unroll
    for (int ky = 0; ky < 3; ky++) {
      int lr = 2 * ohl + ky;
      float4 ev = *(float4*)&E[ci][lr][ow0];
      float4 od = *(float4*)&O[ci][lr][ow0];
      float o4 = O[ci][lr][ow0 + 4];
      const float* wr = w1t + (ci * 9 + ky * 3) * 128 + coB;
#pragma unroll
      for (int q = 0; q < 8; q++) {
        float wa = wr[q], wb = wr[128 + q], wc = wr[256 + q];
        acc[q].x = fmaf(wa, od.x, acc[q].x);
        acc[q].x = fmaf(wb, ev.x, acc[q].x);
        acc[q].x = fmaf(wc, od.y, acc[q].x);
        acc[q].y = fmaf(wa, od.y, acc[q].y);
        acc[q].y = fmaf(wb, ev.y, acc[q].y);
        acc[q].y = fmaf(wc, od.z, acc[q].y);
        acc[q].z = fmaf(wa, od.z, acc[q].z);
        acc[q].z = fmaf(wb, ev.z, acc[q].z);
        acc[q].z = fmaf(wc, od.w, acc[q].z);
        acc[q].w = fmaf(wa, od.w, acc[q].w);
        acc[q].w = fmaf(wb, ev.w, acc[q].w);
        acc[q].w = fmaf(wc, o4,   acc[q].w);
      }
    }
  }
  int g = coB >> 3;
  int pbase = ((g * 32 + b) * 64 + oh) * 64;
#pragma unroll
  for (int oi = 0; oi < 4; oi++) {
    f16x8 hv;
#pragma unroll
    for (int q = 0; q < 8; q++)
      hv[q] = (_Float16)fmaxf(((const float*)&acc[q])[oi], 0.f);
    *(f16x8*)&h1h[(pbase + ow0 + oi) * 8] = hv;
  }
}

// ---------- conv2: fat-step all-LDS compute + fused 4x4 mean-pool ----------
#define C2_ACHUNK 4420                          // 4*17*65
#define C2_WCHUNK 4680
#define C2_WOFF (C2_ACHUNK * 8)                 // f16 offset of weight region
#define C2_LDSB ((C2_ACHUNK + C2_WCHUNK) * 16)  // 145600 bytes
#define C2_STEP 4194304                         // h1 advance per +32ci step
#define C2_WADV 4096                            // WS f16 advance per step

__global__ __launch_bounds__(512, 2) void k_conv2(const _Float16* __restrict__ h1h,
                                                  const _Float16* __restrict__ WS,
                                                  const float* __restrict__ b2,
                                                  float* __restrict__ h2p) {
  extern __shared__ _Float16 L[];
  int bx = blockIdx.x;
  int cohalf = bx & 1;
  int bq = bx >> 1;
  int b = bq >> 2, ohq = bq & 3;
  int oh0 = ohq * 8;
  int tid = threadIdx.x;
  int w = tid >> 6, l = tid & 63;
  int cw = w & 1, rw = w >> 1;
  int ln = l & 15, quad = l >> 4;

  // ---- act staging descriptors: 9 chunks/thread (tail tid<324) ----
  int cursA[9];
  int advA[9];
#pragma unroll
  for (int k = 0; k < 9; k++) {
    int c = (k < 8) ? (tid + k * 512) : (4096 + tid);
    if (c < C2_ACHUNK) {
      int q = c / 65, rem = c - q * 65;
      int ph = rem >= 33;
      int u = ph ? rem - 33 : rem;
      int r = q % 17, g = q / 17;
      int iw = ph ? 2 * u : 2 * u - 1;
      int ih = 2 * oh0 - 1 + r;
      bool ok = (ih >= 0) && (iw >= 0) && (iw < 64);
      cursA[k] = ok ? ((g * 32 + b) * 64 + ih) * 512 + iw * 8 : H1N;
      advA[k] = ok ? C2_STEP : 0;
    } else {
      cursA[k] = H1N;
      advA[k] = 0;
    }
  }
  // ---- weight staging descriptors: 10 chunks/thread (tail tid<72) ----
  int cursW[10];
#pragma unroll
  for (int k = 0; k < 10; k++) {
    int c = (k < 9) ? (tid + k * 512) : (4608 + tid);
    if (c < C2_WCHUNK) {
      int q65 = c / 65, u = c - q65 * 65;
      if (u > 63) u = 63;  // pad slot: stage harmless duplicate
      int pl = q65 >= 36;
      int r36 = q65 - pl * 36;
      int t = r36 >> 2, ci8 = r36 & 3;
      cursW[k] = ((pl * 9 + t) * 16 + ci8) * 1024 + (cohalf * 64 + u) * 8;
    } else {
      cursW[k] = 0;
    }
  }

  f32x4 acc[2][4] = {};  // [cs][s]
  for (int step = 0; step < 4; step++) {
    if (step) __syncthreads();  // prior compute done reading L
    // ---- stage acts(step) ----
#pragma unroll
    for (int k = 0; k < 8; k++) {
      __builtin_amdgcn_global_load_lds(
          (const __attribute__((address_space(1))) void*)(h1h + cursA[k]),
          (__attribute__((address_space(3))) void*)&L[(tid + k * 512) * 8],
          16, 0, 0);
      cursA[k] += advA[k];
    }
    if (tid < 324)
      __builtin_amdgcn_global_load_lds(
          (const __attribute__((address_space(1))) void*)(h1h + cursA[8]),
          (__attribute__((address_space(3))) void*)&L[(4096 + tid) * 8],
          16, 0, 0);
    cursA[8] += advA[8];
    // ---- stage weights(step) ----
#pragma unroll
    for (int k = 0; k < 9; k++) {
      __builtin_amdgcn_global_load_lds(
          (const __attribute__((address_space(1))) void*)(WS + cursW[k]),
          (__attribute__((address_space(3))) void*)&L[C2_WOFF +
                                                     (tid + k * 512) * 8],
          16, 0, 0);
      cursW[k] += C2_WADV;
    }
    if (tid < 72)
      __builtin_amdgcn_global_load_lds(
          (const __attribute__((address_space(1))) void*)(WS + cursW[9]),
          (__attribute__((address_space(3))) void*)&L[C2_WOFF +
                                                     (4608 + tid) * 8],
          16, 0, 0);
    cursW[9] += C2_WADV;
    __syncthreads();  // drain: acts + weights resident

    // ---- compute: pure LDS + MFMA (144 MFMA/wave/step) ----
#pragma unroll
    for (int ky = 0; ky < 3; ky++) {
#pragma unroll
      for (int kx = 0; kx < 3; kx++) {
        int t = ky * 3 + kx;
        int wb = (t * 4 + quad) * 65 + cw * 32 + ln;
        f16x8 Ah0 = *(const f16x8*)&L[C2_WOFF + wb * 8];
        f16x8 Ah1 = *(const f16x8*)&L[C2_WOFF + (wb + 16) * 8];
        f16x8 Al0 = *(const f16x8*)&L[C2_WOFF + (wb + 2340) * 8];
        f16x8 Al1 = *(const f16x8*)&L[C2_WOFF + (wb + 2356) * 8];
#pragma unroll
        for (int s = 0; s < 4; s++) {
          int owl = (s & 1) * 16 + ln;
          int r = 4 * rw + 2 * (s >> 1) + ky;
          int abase = (quad * 17 + r) * 65;
          int uoff = (kx == 1) ? (33 + owl) : (owl + (kx == 2));
          f16x8 Bh = *(const f16x8*)&L[(abase + uoff) * 8];
          acc[0][s] = __builtin_amdgcn_mfma_f32_16x16x32_f16(Al0, Bh, acc[0][s], 0, 0, 0);
          acc[0][s] = __builtin_amdgcn_mfma_f32_16x16x32_f16(Ah0, Bh, acc[0][s], 0, 0, 0);
          acc[1][s] = __builtin_amdgcn_mfma_f32_16x16x32_f16(Al1, Bh, acc[1][s], 0, 0, 0);
          acc[1][s] = __builtin_amdgcn_mfma_f32_16x16x32_f16(Ah1, Bh, acc[1][s], 0, 0, 0);
        }
      }
    }
  }
  // ---- epilogue: fused 4x4 mean-pool ----
  __syncthreads();  // all waves done reading L; reuse act region as h2s
  float* h2s = (float*)L;  // [64co][8row][32col] = 65536 B < 70720 B
#pragma unroll
  for (int cs = 0; cs < 2; cs++)
#pragma unroll
    for (int s = 0; s < 4; s++) {
      int row = 2 * rw + (s >> 1);
      int col = (s & 1) * 16 + ln;
#pragma unroll
      for (int r2 = 0; r2 < 4; r2++) {
        int co64 = cw * 32 + cs * 16 + quad * 4 + r2;
        int co = cohalf * 64 + co64;
        h2s[(co64 * 8 + row) * 32 + col] = fmaxf(acc[cs][s][r2] + b2[co], 0.f);
      }
    }
  __syncthreads();
  // 1024 pool cells (64co x 2pr x 8pc); v19 poolproj's exact add order
  for (int c = tid; c < 1024; c += 512) {
    int co64 = c >> 4, rem = c & 15;
    int pr = rem >> 3, pc = rem & 7;
    const float* base = &h2s[(co64 * 8 + pr * 4) * 32 + pc * 4];
    float s = 0.f;
#pragma unroll
    for (int rr = 0; rr < 4; rr++) {
      s += base[rr * 32 + 0];
      s += base[rr * 32 + 1];
      s += base[rr * 32 + 2];
      s += base[rr * 32 + 3];
    }
    h2p[((b * 128 + cohalf * 64 + co64) * 8 + (2 * ohq + pr)) * 8 + pc] =
        s * 0.0625f;
  }
}

// ---------- proj(1x1,128->64) on pooled input; grid 128 (b x quarter) -------
__global__ __launch_bounds__(256) void k_poolproj(const float* __restrict__ h2p,
                                                  const float* __restrict__ wpT,
                                                  const float* __restrict__ pb,
                                                  float* __restrict__ z_e_out,
                                                  float* __restrict__ lossacc) {
  __shared__ float hp[128][16];
  __shared__ float Ws[128][64];
  int bx = blockIdx.x, tid = threadIdx.x;
  int b = bx >> 2, quarter = bx & 3;
  if (bx == 0 && tid == 0) lossacc[0] = 0.f;
  for (int i = tid; i < 8192; i += 256) Ws[i >> 6][i & 63] = wpT[i];
  for (int i = tid; i < 2048; i += 256) {
    int ci = i >> 4, pl = i & 15;
    hp[ci][pl] = h2p[(b * 128 + ci) * 64 + quarter * 16 + pl];
  }
  __syncthreads();
  int d = tid >> 2, s0 = (tid & 3) * 4;
  float4 acc = make_float4(0.f, 0.f, 0.f, 0.f);
  for (int k = 0; k < 128; k++) {
    float a = Ws[k][d];
    float4 h = *(float4*)&hp[k][s0];
    acc.x = fmaf(a, h.x, acc.x);
    acc.y = fmaf(a, h.y, acc.y);
    acc.z = fmaf(a, h.z, acc.z);
    acc.w = fmaf(a, h.w, acc.w);
  }
  float bv = pb[d];
  float4 r4 = make_float4(acc.x + bv, acc.y + bv, acc.z + bv, acc.w + bv);
  *(float4*)&z_e_out[(b * 64 + d) * 64 + quarter * 16 + s0] = r4;
}

// ---------- VQ argmin + loss + dproj; grid 512 x 256: 4 sites/block ---------
// Block (b, piq) handles sites pi0..pi0+3. Wave w owns codes [w*128, +128),
// 2/lane; cbT values loaded ONCE per d-step, reused across 4 sites.
// #pragma unroll 1 on j- and d-loops pins register pressure (v21 spilled at
// full unroll: VGPR=256, 58 MB scratch). FMA order identical -> outputs
// bit-identical to v15.
__global__ __launch_bounds__(256) void k_vqdproj(const float* __restrict__ z_e,
                                                 const float* __restrict__ cbT,
                                                 const float* __restrict__ cb,
                                                 const float* __restrict__ wdT,
                                                 const float* __restrict__ db,
                                                 float* __restrict__ idx_f,
                                                 _Float16* __restrict__ Yh,
                                                 _Float16* __restrict__ Yl,
                                                 float* __restrict__ loss_acc) {
  __shared__ float zs[4][64];
  __shared__ float zqv[4][64];
  __shared__ double wbst[4][4];  // [site][wave]
  __shared__ int wbi[4][4];
  int bx = blockIdx.x, tid = threadIdx.x;
  int b = bx >> 4, piq = bx & 15;
  int pi0 = piq * 4;
  {
    int site = tid & 3, d = tid >> 2;
    if (tid < 256) zs[site][d] = z_e[(b * 64 + d) * 64 + pi0 + site];
  }
  if (bx == 0 && tid < 64) {  // zero tail page for shifted reads in k_dec
    Yh[YTAIL + tid] = (_Float16)0.f;
    Yh[YTAIL + 64 + tid] = (_Float16)0.f;
    Yl[YTAIL + tid] = (_Float16)0.f;
    Yl[YTAIL + 64 + tid] = (_Float16)0.f;
  }
  __syncthreads();
  int w = tid >> 6, lane = tid & 63;
  double best[4];
  int bi[4];
#pragma unroll
  for (int s2 = 0; s2 < 4; s2++) { best[s2] = 1e300; bi[s2] = 0; }
#pragma unroll 1
  for (int j = 0; j < 2; j++) {
    int k = w * 128 + j * 64 + lane;
    double a[4][4];
#pragma unroll
    for (int s2 = 0; s2 < 4; s2++)
#pragma unroll
      for (int q = 0; q < 4; q++) a[s2][q] = 0.0;
#pragma unroll 1
    for (int d = 0; d < 64; d += 4) {
      double c0 = (double)cbT[d * 512 + k];
      double c1 = (double)cbT[(d + 1) * 512 + k];
      double c2 = (double)cbT[(d + 2) * 512 + k];
      double c3 = (double)cbT[(d + 3) * 512 + k];
#pragma unroll
      for (int s2 = 0; s2 < 4; s2++) {
        double f0 = (double)zs[s2][d] - c0;
        double f1 = (double)zs[s2][d + 1] - c1;
        double f2 = (double)zs[s2][d + 2] - c2;
        double f3 = (double)zs[s2][d + 3] - c3;
        a[s2][0] = fma(f0, f0, a[s2][0]);
        a[s2][1] = fma(f1, f1, a[s2][1]);
        a[s2][2] = fma(f2, f2, a[s2][2]);
        a[s2][3] = fma(f3, f3, a[s2][3]);
      }
    }
#pragma unroll
    for (int s2 = 0; s2 < 4; s2++) {
      double accv = (a[s2][0] + a[s2][1]) + (a[s2][2] + a[s2][3]);
      if (accv < best[s2]) { best[s2] = accv; bi[s2] = k; }
    }
  }
#pragma unroll
  for (int s2 = 0; s2 < 4; s2++) {
    double bb = best[s2];
    int bix = bi[s2];
    for (int m = 1; m < 64; m <<= 1) {
      double ob = __shfl_xor(bb, m, 64);
      int oi = __shfl_xor(bix, m, 64);
      if (ob < bb || (ob == bb && oi < bix)) { bb = ob; bix = oi; }
    }
    if (lane == 0) { wbst[s2][w] = bb; wbi[s2][w] = bix; }
  }
  __syncthreads();
  {  // site s2 = w handled by wave w: fold ascending, loss, zq stage
    int s2 = w;
    double bb = wbst[s2][0];
    int bix = wbi[s2][0];
#pragma unroll
    for (int q = 1; q < 4; q++) {
      double ob = wbst[s2][q];
      int oi = wbi[s2][q];
      if (ob < bb || (ob == bb && oi < bix)) { bb = ob; bix = oi; }
    }
    int n = b * 64 + pi0 + s2;
    float zq_l = cb[bix * 64 + lane];
    float e = zq_l - zs[s2][lane];
    float sq = e * e;
    for (int m = 1; m < 64; m <<= 1) sq += __shfl_xor(sq, m, 64);
    if (lane == 0) {
      idx_f[n] = (float)bix;
      atomicAdd(loss_acc, sq);
    }
    zqv[s2][lane] = zq_l;
  }
  __syncthreads();
  for (int i = tid; i < 512; i += 256) {  // dproj: (site, co) per output
    int s2 = i >> 7, co = i & 127;
    int n = b * 64 + pi0 + s2;
    float a = db[co];
#pragma unroll 4
    for (int d = 0; d < 64; d++) a = fmaf(wdT[d * 128 + co], zqv[s2][d], a);
    float y = fmaxf(a, 0.f);
    _Float16 h = (_Float16)y;
    Yh[n * 128 + co] = h;
    Yl[n * 128 + co] = (_Float16)(y - (float)h);
  }
}

// ---------- dec: per-CLASS accumulated f16-split MFMA -> Tb[9][2048][128] ---
__global__ __launch_bounds__(256) void k_dec(const _Float16* __restrict__ Yh,
                                             const _Float16* __restrict__ Yl,
                                             const _Float16* __restrict__ Ah,
                                             const _Float16* __restrict__ Al,
                                             const float* __restrict__ bc1,
                                             float* __restrict__ Tb) {
  int bxx = blockIdx.x;
  int cls = bxx >> 6, n_t = bxx & 63;
  int rc = cls / 3, c3 = cls - rc * 3;
  const int rset[3][2] = {{0, 1}, {2, 2}, {3, 4}};
  const int rcnt[3] = {2, 1, 2};
  int w = threadIdx.x >> 6, l = threadIdx.x & 63;
  int ln = l & 15, quad = l >> 4;
  int coW = w * 32;
  int nB = n_t * 32;
  int kq = quad * 8;
  f32x4 acc[2][2] = {};
  for (int iy = 0; iy < rcnt[rc]; iy++) {
    int py = rset[rc][iy];
    int dy = (py == 0) ? -1 : ((py == 4) ? 1 : 0);
    for (int ix = 0; ix < rcnt[c3]; ix++) {
      int px = rset[c3][ix];
      int dx = (px == 0) ? -1 : ((px == 4) ? 1 : 0);
      int pq = py * 5 + px;
      int src[2];
#pragma unroll
      for (int s = 0; s < 2; s++) {
        int n = nB + s * 16 + ln;
        int bb = n >> 6, s6 = n & 63;
        int sy = (s6 >> 3) + dy, sx = (s6 & 7) + dx;
        bool ok = ((unsigned)sy < 8u) && ((unsigned)sx < 8u);
        src[s] = ok ? ((bb * 64 + sy * 8 + sx) * 128) : YTAIL;
      }
#pragma unroll 2
      for (int ci0 = 0; ci0 < 128; ci0 += 32) {
        const int wbase = (pq * 128 + coW + ln) * 128 + ci0 + kq;
        f16x8 Ah0 = *(const f16x8*)&Ah[wbase];
        f16x8 Al0 = *(const f16x8*)&Al[wbase];
        f16x8 Ah1 = *(const f16x8*)&Ah[wbase + 2048];
        f16x8 Al1 = *(const f16x8*)&Al[wbase + 2048];
        f16x8 Bh[2], Bl[2];
#pragma unroll
        for (int s = 0; s < 2; s++) {
          Bh[s] = *(const f16x8*)&Yh[src[s] + ci0 + kq];
          Bl[s] = *(const f16x8*)&Yl[src[s] + ci0 + kq];
        }
#pragma unroll
        for (int cs = 0; cs < 2; cs++) {
          f16x8 ah = cs ? Ah1 : Ah0;
          f16x8 al = cs ? Al1 : Al0;
#pragma unroll
          for (int s = 0; s < 2; s++) {
            acc[cs][s] = __builtin_amdgcn_mfma_f32_16x16x32_f16(al, Bh[s], acc[cs][s], 0, 0, 0);
            acc[cs][s] = __builtin_amdgcn_mfma_f32_16x16x32_f16(ah, Bl[s], acc[cs][s], 0, 0, 0);
            acc[cs][s] = __builtin_amdgcn_mfma_f32_16x16x32_f16(ah, Bh[s], acc[cs][s], 0, 0, 0);
          }
        }
      }
    }
  }
  // epilogue: bc1 + relu, write Tb[cls][site][co]
#pragma unroll
  for (int cs = 0; cs < 2; cs++)
#pragma unroll
    for (int s = 0; s < 2; s++) {
      int site = nB + s * 16 + ln;
      int co0 = coW + cs * 16 + quad * 4;
      float4 bv = *(const float4*)&bc1[co0];
      float4 g = make_float4(fmaxf(acc[cs][s][0] + bv.x, 0.f),
                             fmaxf(acc[cs][s][1] + bv.y, 0.f),
                             fmaxf(acc[cs][s][2] + bv.z, 0.f),
                             fmaxf(acc[cs][s][3] + bv.w, 0.f));
      *(float4*)&Tb[(cls * 2048 + site) * 128 + co0] = g;
    }
}

// ---------- out: read Tb, 1x1 conv to 3ch, splat ----------------------------
__global__ __launch_bounds__(256) void k_out(const float* __restrict__ TbG,
                                             const float* __restrict__ w3,
                                             const float* __restrict__ b3,
                                             float* __restrict__ xhat,
                                             const float* __restrict__ loss_acc,
                                             float* __restrict__ out_loss) {
  __shared__ float Tb[9][128];
  __shared__ float part[9][3][8];
  __shared__ float vals[9][3];
  int bj = blockIdx.x, bi = blockIdx.y, b = blockIdx.z;
  int s = bi * 8 + bj;
  int n = b * 64 + s;
  int tid = threadIdx.x;
  if (bj == 0 && bi == 0 && b == 0 && tid == 0)
    out_loss[0] = loss_acc[0] * 1.25f / 131072.0f;
  for (int i = tid; i < 1152; i += 256) {
    int cls = i >> 7, co = i & 127;
    Tb[cls][co] = TbG[(cls * 2048 + n) * 128 + co];
  }
  __syncthreads();
  if (tid < 216) {
    int cls = tid / 24, rem = tid - cls * 24;
    int cc = rem >> 3, seg = rem & 7;
    float ss = 0.f;
#pragma unroll
    for (int d = 0; d < 16; d++) ss = fmaf(w3[cc * 128 + seg * 16 + d], Tb[cls][seg * 16 + d], ss);
    part[cls][cc][seg] = ss;
  }
  __syncthreads();
  if (tid < 27) {
    int cls = tid / 3, cc = tid - cls * 3;
    float ss = b3[cc];
#pragma unroll
    for (int seg = 0; seg < 8; seg++) ss += part[cls][cc][seg];
    vals[cls][cc] = ss;
  }
  __syncthreads();
  for (int i = tid; i < 768; i += 256) {
    int cc = i >> 8, p = i & 255;
    int ry = p >> 4, rx = p & 15;
    int rcls = (ry == 0) ? 0 : ((ry == 15) ? 2 : 1);
    int ccls = (rx == 0) ? 0 : ((rx == 15) ? 2 : 1);
    xhat[((b * 3 + cc) * 128 + bi * 16 + ry) * 128 + bj * 16 + rx] =
        vals[rcls * 3 + ccls][cc];
  }
}

extern "C" void kernel_launch(void* const* d_in, const int* in_sizes, int n_in,
                              void* d_out, int out_size, void* d_ws, size_t ws_size,
                              hipStream_t stream) {
  const float* x   = (const float*)d_in[0];
  const float* w1  = (const float*)d_in[1];
  const float* b1  = (const float*)d_in[2];
  const float* w2  = (const float*)d_in[3];
  const float* b2  = (const float*)d_in[4];
  const float* wp  = (const float*)d_in[5];
  const float* pb  = (const float*)d_in[6];
  const float* cb  = (const float*)d_in[7];
  const float* wd  = (const float*)d_in[8];
  const float* db  = (const float*)d_in[9];
  const float* wc1 = (const float*)d_in[10];
  const float* bc1 = (const float*)d_in[11];
  const float* wc2 = (const float*)d_in[12];
  const float* bc2 = (const float*)d_in[13];
  float* out = (float*)d_out;
  float* ws  = (float*)d_ws;

  // workspace (float offsets):
  _Float16* h1h = (_Float16*)(ws);             // [0, 8388640) f16 plane (+tail)
  float* h2p    = ws + 16777280;               // 262144 (pooled)
  _Float16* WS  = (_Float16*)(ws + 20971584);  // 147456 fl (294912 f16)
  float* w1t    = ws + 21119040;               // 3456
  float* wpT    = ws + 21122496;               // 8192
  float* wdT    = ws + 21130688;               // 8192
  float* cbT    = ws + 21138880;               // 32768
  _Float16* Ahd = (_Float16*)(ws + 21171648);  // 204800 fl
  _Float16* Ald = (_Float16*)(ws + 21376448);  // 204800 fl -> end 21581248
  // overlays inside dead h1h region (valid after conv2):
  float* Tb      = ws;                         // [0, 2359296) 9*2048*128
  _Float16* Yh   = (_Float16*)(ws + 6553600);  // 131136 fl (2049*128 f16)
  _Float16* Yl   = (_Float16*)(ws + 6684736);  // 131136 fl
  float* lossacc = ws + 6815872;               // 1

  float* o_xhat = out;
  float* o_idx  = out + 1572864;
  float* o_loss = out + 1574912;
  float* o_ze   = out + 1574913;

  static bool s_attr_done = false;
  if (!s_attr_done) {
    (void)hipFuncSetAttribute((const void*)k_conv2,
                              hipFuncAttributeMaxDynamicSharedMemorySize, C2_LDSB);
    s_attr_done = true;
  }

  k_prep<<<dim3(153), 256, 0, stream>>>(w2, w1, wp, wd, wc1, cb,
                                        w1t, wpT, wdT, cbT, Ahd, Ald, WS, h1h);
  k_conv1<<<dim3(4, 16, 32), 256, 0, stream>>>(x, w1t, b1, h1h);
  k_conv2<<<dim3(256), 512, C2_LDSB, stream>>>(h1h, WS, b2, h2p);
  k_poolproj<<<dim3(128), 256, 0, stream>>>(h2p, wpT, pb, o_ze, lossacc);
  k_vqdproj<<<dim3(512), 256, 0, stream>>>(o_ze, cbT, cb, wdT, db, o_idx, Yh, Yl, lossacc);
  k_dec<<<dim3(576), 256, 0, stream>>>(Yh, Yl, Ahd, Ald, bc1, Tb);
  k_out<<<dim3(8, 8, 32), 256, 0, stream>>>(Tb, wc2, bc2, o_xhat, lossacc, o_loss);
}

// Round 15
// 224.982 us; speedup vs baseline: 1.2044x; 1.0407x over previous
//
#include <hip/hip_runtime.h>
#include <math.h>

// ---------------------------------------------------------------------------
// VQVAE forward. v23: vqdproj reverted to the v15/v20 kernel (grid 2048,
// 4 waves, 15 us). The cbT-reuse arc (v21: full-unroll spill, VGPR=256,
// 58 MB scratch; v22: unroll-1 serialization + 4x less TLP -> 49 us despite
// FETCH 20->2.7 MB) showed the kernel's 15 us comes from 32 waves/CU hiding
// L2 latency -- reuse that halves TLP loses more than the traffic saves.
// Everything else unchanged from v20 (fused pool conv2, class-fused dec,
// proj-only poolproj).
// ---------------------------------------------------------------------------

typedef _Float16 f16x8 __attribute__((ext_vector_type(8)));
typedef float f32x4 __attribute__((ext_vector_type(4)));

#define H1N 16777216        // elements in h1 plane; zero tail after
#define YTAIL (2048 * 128)  // zero page in Yh/Yl for OOB shifts

// ---------- prep: A-agg (0..127), W-layout (128..143), cbT (144..151), misc -
__global__ __launch_bounds__(256) void k_prep(const float* __restrict__ w2,
                                              const float* __restrict__ w1,
                                              const float* __restrict__ wp,
                                              const float* __restrict__ wd,
                                              const float* __restrict__ wd1,
                                              const float* __restrict__ cb,
                                              float* __restrict__ w1t,
                                              float* __restrict__ wpT,
                                              float* __restrict__ wdT,
                                              float* __restrict__ cbT,
                                              _Float16* __restrict__ Ah,
                                              _Float16* __restrict__ Al,
                                              _Float16* __restrict__ WS,
                                              _Float16* __restrict__ h1h) {
  int bx = blockIdx.x, tid = threadIdx.x;
  if (bx < 128) {  // ---- A aggregation, block = co, lanes = ci (writes coalesced)
    __shared__ float wrow[1152];
    int co = bx;
    for (int i = tid; i < 1152; i += 256) wrow[i] = wd1[co * 1152 + i];
    __syncthreads();
    if (tid < 128) {
      int ci = tid;
      float w[9];
#pragma unroll
      for (int t = 0; t < 9; t++) w[t] = wrow[ci * 9 + t];
      float rx[3][5];
#pragma unroll
      for (int ky = 0; ky < 3; ky++) {
        float a0 = w[ky * 3 + 0], a1 = w[ky * 3 + 1], a2 = w[ky * 3 + 2];
        rx[ky][0] = a0; rx[ky][1] = a1 + a2; rx[ky][2] = a0 + a1 + a2;
        rx[ky][3] = a0 + a1; rx[ky][4] = a2;
      }
#pragma unroll
      for (int px = 0; px < 5; px++) {
        float s0 = rx[0][px], s1 = rx[1][px], s2 = rx[2][px];
        float ry[5];
        ry[0] = s0; ry[1] = s1 + s2; ry[2] = s0 + s1 + s2; ry[3] = s0 + s1; ry[4] = s2;
#pragma unroll
        for (int py = 0; py < 5; py++) {
          int pq = py * 5 + px;
          float v = ry[py];
          _Float16 h = (_Float16)v;
          int o = (pq * 128 + co) * 128 + ci;
          Ah[o] = h;
          Al[o] = (_Float16)(v - (float)h);
        }
      }
    }
    return;
  }
  if (bx < 144) {  // ---- W layout for conv2 staging: [pl][tap][ci8g][co]x8
    __shared__ float wst[9216];
    int co0 = (bx - 128) * 8;
    for (int i = tid; i < 9216; i += 256) wst[i] = w2[co0 * 1152 + i];
    __syncthreads();
    for (int i = tid; i < 9216; i += 256) {
      int co = i / 1152, r = i - co * 1152;
      int tap = r >> 7, ci = r & 127;
      float v = wst[co * 1152 + ci * 9 + tap];
      _Float16 h = (_Float16)v;
      int og = ((tap * 16 + (ci >> 3)) * 128 + co0 + co) * 8 + (ci & 7);
      WS[og] = h;                                   // pl = 0 (high)
      WS[og + 147456] = (_Float16)(v - (float)h);   // pl = 1 (low); 9*16*128*8
    }
    return;
  }
  if (bx < 152) {  // ---- cbT tile transpose (64 k x 64 d), padded LDS
    __shared__ float cbs[64 * 65];
    int k0 = (bx - 144) * 64;
    for (int i = tid; i < 4096; i += 256) {
      int k = i >> 6, d = i & 63;
      cbs[k * 65 + d] = cb[(k0 + k) * 64 + d];
    }
    __syncthreads();
    for (int i = tid; i < 4096; i += 256) {
      int d = i >> 6, k = i & 63;
      cbT[d * 512 + k0 + k] = cbs[k * 65 + d];
    }
    return;
  }
  // ---- misc small transposes + h1 zero tail (writes lane-contiguous)
  for (int i = tid; i < 3456; i += 256) {  // w1t[t][co] = w1[co][t]
    int co = i & 127, t = i >> 7;
    w1t[t * 128 + co] = w1[co * 27 + t];
  }
  for (int i = tid; i < 8192; i += 256) {  // wpT[k][d] = wp[d][k]
    int d = i & 63, k = i >> 6;
    wpT[k * 64 + d] = wp[d * 128 + k];
  }
  for (int i = tid; i < 8192; i += 256) {  // wdT[d][co] = wd[co][d]
    int co = i & 127, d = i >> 7;
    wdT[d * 128 + co] = wd[co * 64 + d];
  }
  if (tid < 64) h1h[H1N + tid] = (_Float16)0.f;
}

// ---------- conv1: (32,3,128,128) -> h1 f16 [g][b][oh][ow][8ci] -------------
__global__ __launch_bounds__(256) void k_conv1(const float* __restrict__ x,
                                               const float* __restrict__ w1t,
                                               const float* __restrict__ b1,
                                               _Float16* __restrict__ h1h) {
  __shared__ float E[3][9][68];
  __shared__ float O[3][9][68];
  int co_t = blockIdx.x, oh_t = blockIdx.y, b = blockIdx.z;
  int oh0 = oh_t * 4;
  int tid = threadIdx.x;
  int wv = __builtin_amdgcn_readfirstlane(tid >> 6);
  int l = tid & 63;
  int coB = co_t * 32 + wv * 8;

  for (int idx = tid; idx < 1728; idx += 256) {
    int p = idx & 63, r = idx >> 6;
    int ci = r / 9, lr = r - ci * 9;
    int ih = 2 * oh0 - 1 + lr;
    float2 v = make_float2(0.f, 0.f);
    if ((unsigned)ih < 128u)
      v = *(const float2*)&x[((b * 3 + ci) * 128 + ih) * 128 + 2 * p];
    E[ci][lr][p] = v.x;
    O[ci][lr][p + 1] = v.y;
  }
  if (tid < 27) {
    int ci = tid / 9, lr = tid - ci * 9;
    O[ci][lr][0] = 0.f;
  }
  __syncthreads();

  int ohl = l >> 4, ow0 = (l & 15) * 4;
  int oh = oh0 + ohl;
  float4 acc[8];
#pragma unroll
  for (int q = 0; q < 8; q++) {
    float bv = b1[coB + q];
    acc[q] = make_float4(bv, bv, bv, bv);
  }
#pragma unroll
  for (int ci = 0; ci < 3; ci++) {
#pragma unroll
    for (int ky = 0; ky < 3; ky++) {
      int lr = 2 * ohl + ky;
      float4 ev = *(float4*)&E[ci][lr][ow0];
      float4 od = *(float4*)&O[ci][lr][ow0];
      float o4 = O[ci][lr][ow0 + 4];
      const float* wr = w1t + (ci * 9 + ky * 3) * 128 + coB;
#pragma unroll
      for (int q = 0; q < 8; q++) {
        float wa = wr[q], wb = wr[128 + q], wc = wr[256 + q];
        acc[q].x = fmaf(wa, od.x, acc[q].x);
        acc[q].x = fmaf(wb, ev.x, acc[q].x);
        acc[q].x = fmaf(wc, od.y, acc[q].x);
        acc[q].y = fmaf(wa, od.y, acc[q].y);
        acc[q].y = fmaf(wb, ev.y, acc[q].y);
        acc[q].y = fmaf(wc, od.z, acc[q].y);
        acc[q].z = fmaf(wa, od.z, acc[q].z);
        acc[q].z = fmaf(wb, ev.z, acc[q].z);
        acc[q].z = fmaf(wc, od.w, acc[q].z);
        acc[q].w = fmaf(wa, od.w, acc[q].w);
        acc[q].w = fmaf(wb, ev.w, acc[q].w);
        acc[q].w = fmaf(wc, o4,   acc[q].w);
      }
    }
  }
  int g = coB >> 3;
  int pbase = ((g * 32 + b) * 64 + oh) * 64;
#pragma unroll
  for (int oi = 0; oi < 4; oi++) {
    f16x8 hv;
#pragma unroll
    for (int q = 0; q < 8; q++)
      hv[q] = (_Float16)fmaxf(((const float*)&acc[q])[oi], 0.f);
    *(f16x8*)&h1h[(pbase + ow0 + oi) * 8] = hv;
  }
}

// ---------- conv2: fat-step all-LDS compute + fused 4x4 mean-pool ----------
#define C2_ACHUNK 4420                          // 4*17*65
#define C2_WCHUNK 4680
#define C2_WOFF (C2_ACHUNK * 8)                 // f16 offset of weight region
#define C2_LDSB ((C2_ACHUNK + C2_WCHUNK) * 16)  // 145600 bytes
#define C2_STEP 4194304                         // h1 advance per +32ci step
#define C2_WADV 4096                            // WS f16 advance per step

__global__ __launch_bounds__(512, 2) void k_conv2(const _Float16* __restrict__ h1h,
                                                  const _Float16* __restrict__ WS,
                                                  const float* __restrict__ b2,
                                                  float* __restrict__ h2p) {
  extern __shared__ _Float16 L[];
  int bx = blockIdx.x;
  int cohalf = bx & 1;
  int bq = bx >> 1;
  int b = bq >> 2, ohq = bq & 3;
  int oh0 = ohq * 8;
  int tid = threadIdx.x;
  int w = tid >> 6, l = tid & 63;
  int cw = w & 1, rw = w >> 1;
  int ln = l & 15, quad = l >> 4;

  // ---- act staging descriptors: 9 chunks/thread (tail tid<324) ----
  int cursA[9];
  int advA[9];
#pragma unroll
  for (int k = 0; k < 9; k++) {
    int c = (k < 8) ? (tid + k * 512) : (4096 + tid);
    if (c < C2_ACHUNK) {
      int q = c / 65, rem = c - q * 65;
      int ph = rem >= 33;
      int u = ph ? rem - 33 : rem;
      int r = q % 17, g = q / 17;
      int iw = ph ? 2 * u : 2 * u - 1;
      int ih = 2 * oh0 - 1 + r;
      bool ok = (ih >= 0) && (iw >= 0) && (iw < 64);
      cursA[k] = ok ? ((g * 32 + b) * 64 + ih) * 512 + iw * 8 : H1N;
      advA[k] = ok ? C2_STEP : 0;
    } else {
      cursA[k] = H1N;
      advA[k] = 0;
    }
  }
  // ---- weight staging descriptors: 10 chunks/thread (tail tid<72) ----
  int cursW[10];
#pragma unroll
  for (int k = 0; k < 10; k++) {
    int c = (k < 9) ? (tid + k * 512) : (4608 + tid);
    if (c < C2_WCHUNK) {
      int q65 = c / 65, u = c - q65 * 65;
      if (u > 63) u = 63;  // pad slot: stage harmless duplicate
      int pl = q65 >= 36;
      int r36 = q65 - pl * 36;
      int t = r36 >> 2, ci8 = r36 & 3;
      cursW[k] = ((pl * 9 + t) * 16 + ci8) * 1024 + (cohalf * 64 + u) * 8;
    } else {
      cursW[k] = 0;
    }
  }

  f32x4 acc[2][4] = {};  // [cs][s]
  for (int step = 0; step < 4; step++) {
    if (step) __syncthreads();  // prior compute done reading L
    // ---- stage acts(step) ----
#pragma unroll
    for (int k = 0; k < 8; k++) {
      __builtin_amdgcn_global_load_lds(
          (const __attribute__((address_space(1))) void*)(h1h + cursA[k]),
          (__attribute__((address_space(3))) void*)&L[(tid + k * 512) * 8],
          16, 0, 0);
      cursA[k] += advA[k];
    }
    if (tid < 324)
      __builtin_amdgcn_global_load_lds(
          (const __attribute__((address_space(1))) void*)(h1h + cursA[8]),
          (__attribute__((address_space(3))) void*)&L[(4096 + tid) * 8],
          16, 0, 0);
    cursA[8] += advA[8];
    // ---- stage weights(step) ----
#pragma unroll
    for (int k = 0; k < 9; k++) {
      __builtin_amdgcn_global_load_lds(
          (const __attribute__((address_space(1))) void*)(WS + cursW[k]),
          (__attribute__((address_space(3))) void*)&L[C2_WOFF +
                                                     (tid + k * 512) * 8],
          16, 0, 0);
      cursW[k] += C2_WADV;
    }
    if (tid < 72)
      __builtin_amdgcn_global_load_lds(
          (const __attribute__((address_space(1))) void*)(WS + cursW[9]),
          (__attribute__((address_space(3))) void*)&L[C2_WOFF +
                                                     (4608 + tid) * 8],
          16, 0, 0);
    cursW[9] += C2_WADV;
    __syncthreads();  // drain: acts + weights resident

    // ---- compute: pure LDS + MFMA (144 MFMA/wave/step) ----
#pragma unroll
    for (int ky = 0; ky < 3; ky++) {
#pragma unroll
      for (int kx = 0; kx < 3; kx++) {
        int t = ky * 3 + kx;
        int wb = (t * 4 + quad) * 65 + cw * 32 + ln;
        f16x8 Ah0 = *(const f16x8*)&L[C2_WOFF + wb * 8];
        f16x8 Ah1 = *(const f16x8*)&L[C2_WOFF + (wb + 16) * 8];
        f16x8 Al0 = *(const f16x8*)&L[C2_WOFF + (wb + 2340) * 8];
        f16x8 Al1 = *(const f16x8*)&L[C2_WOFF + (wb + 2356) * 8];
#pragma unroll
        for (int s = 0; s < 4; s++) {
          int owl = (s & 1) * 16 + ln;
          int r = 4 * rw + 2 * (s >> 1) + ky;
          int abase = (quad * 17 + r) * 65;
          int uoff = (kx == 1) ? (33 + owl) : (owl + (kx == 2));
          f16x8 Bh = *(const f16x8*)&L[(abase + uoff) * 8];
          acc[0][s] = __builtin_amdgcn_mfma_f32_16x16x32_f16(Al0, Bh, acc[0][s], 0, 0, 0);
          acc[0][s] = __builtin_amdgcn_mfma_f32_16x16x32_f16(Ah0, Bh, acc[0][s], 0, 0, 0);
          acc[1][s] = __builtin_amdgcn_mfma_f32_16x16x32_f16(Al1, Bh, acc[1][s], 0, 0, 0);
          acc[1][s] = __builtin_amdgcn_mfma_f32_16x16x32_f16(Ah1, Bh, acc[1][s], 0, 0, 0);
        }
      }
    }
  }
  // ---- epilogue: fused 4x4 mean-pool ----
  __syncthreads();  // all waves done reading L; reuse act region as h2s
  float* h2s = (float*)L;  // [64co][8row][32col] = 65536 B < 70720 B
#pragma unroll
  for (int cs = 0; cs < 2; cs++)
#pragma unroll
    for (int s = 0; s < 4; s++) {
      int row = 2 * rw + (s >> 1);
      int col = (s & 1) * 16 + ln;
#pragma unroll
      for (int r2 = 0; r2 < 4; r2++) {
        int co64 = cw * 32 + cs * 16 + quad * 4 + r2;
        int co = cohalf * 64 + co64;
        h2s[(co64 * 8 + row) * 32 + col] = fmaxf(acc[cs][s][r2] + b2[co], 0.f);
      }
    }
  __syncthreads();
  // 1024 pool cells (64co x 2pr x 8pc); v19 poolproj's exact add order
  for (int c = tid; c < 1024; c += 512) {
    int co64 = c >> 4, rem = c & 15;
    int pr = rem >> 3, pc = rem & 7;
    const float* base = &h2s[(co64 * 8 + pr * 4) * 32 + pc * 4];
    float s = 0.f;
#pragma unroll
    for (int rr = 0; rr < 4; rr++) {
      s += base[rr * 32 + 0];
      s += base[rr * 32 + 1];
      s += base[rr * 32 + 2];
      s += base[rr * 32 + 3];
    }
    h2p[((b * 128 + cohalf * 64 + co64) * 8 + (2 * ohq + pr)) * 8 + pc] =
        s * 0.0625f;
  }
}

// ---------- proj(1x1,128->64) on pooled input; grid 128 (b x quarter) -------
__global__ __launch_bounds__(256) void k_poolproj(const float* __restrict__ h2p,
                                                  const float* __restrict__ wpT,
                                                  const float* __restrict__ pb,
                                                  float* __restrict__ z_e_out,
                                                  float* __restrict__ lossacc) {
  __shared__ float hp[128][16];
  __shared__ float Ws[128][64];
  int bx = blockIdx.x, tid = threadIdx.x;
  int b = bx >> 2, quarter = bx & 3;
  if (bx == 0 && tid == 0) lossacc[0] = 0.f;
  for (int i = tid; i < 8192; i += 256) Ws[i >> 6][i & 63] = wpT[i];
  for (int i = tid; i < 2048; i += 256) {
    int ci = i >> 4, pl = i & 15;
    hp[ci][pl] = h2p[(b * 128 + ci) * 64 + quarter * 16 + pl];
  }
  __syncthreads();
  int d = tid >> 2, s0 = (tid & 3) * 4;
  float4 acc = make_float4(0.f, 0.f, 0.f, 0.f);
  for (int k = 0; k < 128; k++) {
    float a = Ws[k][d];
    float4 h = *(float4*)&hp[k][s0];
    acc.x = fmaf(a, h.x, acc.x);
    acc.y = fmaf(a, h.y, acc.y);
    acc.z = fmaf(a, h.z, acc.z);
    acc.w = fmaf(a, h.w, acc.w);
  }
  float bv = pb[d];
  float4 r4 = make_float4(acc.x + bv, acc.y + bv, acc.z + bv, acc.w + bv);
  *(float4*)&z_e_out[(b * 64 + d) * 64 + quarter * 16 + s0] = r4;
}

// ---------- VQ argmin + loss + dproj; grid 2048 x 256 (4 waves) -------------
// v15's kernel (reverted from the v21/v22 reuse arc): wave w owns codes
// [w*128, w*128+128), 2/lane; per-code f64 math bit-identical to v14's
// 1-wave form; reduction preserves smallest-index-on-tie.
__global__ __launch_bounds__(256) void k_vqdproj(const float* __restrict__ z_e,
                                                 const float* __restrict__ cbT,
                                                 const float* __restrict__ cb,
                                                 const float* __restrict__ wdT,
                                                 const float* __restrict__ db,
                                                 float* __restrict__ idx_f,
                                                 _Float16* __restrict__ Yh,
                                                 _Float16* __restrict__ Yl,
                                                 float* __restrict__ loss_acc) {
  __shared__ float zs[64];
  __shared__ float zqv[64];
  __shared__ double wbst[4];
  __shared__ int wbi[4];
  int n = blockIdx.x, tid = threadIdx.x;
  int b = n >> 6, pi = n & 63;
  if (tid < 64) zs[tid] = z_e[(b * 64 + tid) * 64 + pi];
  if (n == 0 && tid < 64) {  // zero tail page for shifted reads in k_dec
    Yh[YTAIL + tid] = (_Float16)0.f;
    Yh[YTAIL + 64 + tid] = (_Float16)0.f;
    Yl[YTAIL + tid] = (_Float16)0.f;
    Yl[YTAIL + 64 + tid] = (_Float16)0.f;
  }
  __syncthreads();
  int w = tid >> 6, lane = tid & 63;
  double best = 1e300;
  int bi = 0;
#pragma unroll
  for (int j = 0; j < 2; j++) {
    int k = w * 128 + j * 64 + lane;
    double a0 = 0.0, a1 = 0.0, a2 = 0.0, a3 = 0.0;
#pragma unroll 4
    for (int d = 0; d < 64; d += 4) {
      double f0 = (double)zs[d] - (double)cbT[d * 512 + k];
      double f1 = (double)zs[d + 1] - (double)cbT[(d + 1) * 512 + k];
      double f2 = (double)zs[d + 2] - (double)cbT[(d + 2) * 512 + k];
      double f3 = (double)zs[d + 3] - (double)cbT[(d + 3) * 512 + k];
      a0 = fma(f0, f0, a0);
      a1 = fma(f1, f1, a1);
      a2 = fma(f2, f2, a2);
      a3 = fma(f3, f3, a3);
    }
    double acc = (a0 + a1) + (a2 + a3);
    if (acc < best) { best = acc; bi = k; }
  }
  for (int m = 1; m < 64; m <<= 1) {
    double ob = __shfl_xor(best, m, 64);
    int oi = __shfl_xor(bi, m, 64);
    if (ob < best || (ob == best && oi < bi)) { best = ob; bi = oi; }
  }
  if (lane == 0) { wbst[w] = best; wbi[w] = bi; }
  __syncthreads();
  best = wbst[0];
  bi = wbi[0];
#pragma unroll
  for (int q = 1; q < 4; q++) {
    double ob = wbst[q];
    int oi = wbi[q];
    if (ob < best || (ob == best && oi < bi)) { best = ob; bi = oi; }
  }
  if (tid < 64) {  // wave 0: loss + zq staging
    float zq_l = cb[bi * 64 + tid];
    float e = zq_l - zs[tid];
    float sq = e * e;
    for (int m = 1; m < 64; m <<= 1) sq += __shfl_xor(sq, m, 64);
    if (tid == 0) {
      idx_f[n] = (float)bi;
      atomicAdd(loss_acc, sq);
    }
    zqv[tid] = zq_l;
  }
  __syncthreads();
  if (tid < 128) {  // dproj: one co per thread
    float a = db[tid];
#pragma unroll 4
    for (int d = 0; d < 64; d++) a = fmaf(wdT[d * 128 + tid], zqv[d], a);
    float y = fmaxf(a, 0.f);
    _Float16 h = (_Float16)y;
    Yh[n * 128 + tid] = h;
    Yl[n * 128 + tid] = (_Float16)(y - (float)h);
  }
}

// ---------- dec: per-CLASS accumulated f16-split MFMA -> Tb[9][2048][128] ---
__global__ __launch_bounds__(256) void k_dec(const _Float16* __restrict__ Yh,
                                             const _Float16* __restrict__ Yl,
                                             const _Float16* __restrict__ Ah,
                                             const _Float16* __restrict__ Al,
                                             const float* __restrict__ bc1,
                                             float* __restrict__ Tb) {
  int bxx = blockIdx.x;
  int cls = bxx >> 6, n_t = bxx & 63;
  int rc = cls / 3, c3 = cls - rc * 3;
  const int rset[3][2] = {{0, 1}, {2, 2}, {3, 4}};
  const int rcnt[3] = {2, 1, 2};
  int w = threadIdx.x >> 6, l = threadIdx.x & 63;
  int ln = l & 15, quad = l >> 4;
  int coW = w * 32;
  int nB = n_t * 32;
  int kq = quad * 8;
  f32x4 acc[2][2] = {};
  for (int iy = 0; iy < rcnt[rc]; iy++) {
    int py = rset[rc][iy];
    int dy = (py == 0) ? -1 : ((py == 4) ? 1 : 0);
    for (int ix = 0; ix < rcnt[c3]; ix++) {
      int px = rset[c3][ix];
      int dx = (px == 0) ? -1 : ((px == 4) ? 1 : 0);
      int pq = py * 5 + px;
      int src[2];
#pragma unroll
      for (int s = 0; s < 2; s++) {
        int n = nB + s * 16 + ln;
        int bb = n >> 6, s6 = n & 63;
        int sy = (s6 >> 3) + dy, sx = (s6 & 7) + dx;
        bool ok = ((unsigned)sy < 8u) && ((unsigned)sx < 8u);
        src[s] = ok ? ((bb * 64 + sy * 8 + sx) * 128) : YTAIL;
      }
#pragma unroll 2
      for (int ci0 = 0; ci0 < 128; ci0 += 32) {
        const int wbase = (pq * 128 + coW + ln) * 128 + ci0 + kq;
        f16x8 Ah0 = *(const f16x8*)&Ah[wbase];
        f16x8 Al0 = *(const f16x8*)&Al[wbase];
        f16x8 Ah1 = *(const f16x8*)&Ah[wbase + 2048];
        f16x8 Al1 = *(const f16x8*)&Al[wbase + 2048];
        f16x8 Bh[2], Bl[2];
#pragma unroll
        for (int s = 0; s < 2; s++) {
          Bh[s] = *(const f16x8*)&Yh[src[s] + ci0 + kq];
          Bl[s] = *(const f16x8*)&Yl[src[s] + ci0 + kq];
        }
#pragma unroll
        for (int cs = 0; cs < 2; cs++) {
          f16x8 ah = cs ? Ah1 : Ah0;
          f16x8 al = cs ? Al1 : Al0;
#pragma unroll
          for (int s = 0; s < 2; s++) {
            acc[cs][s] = __builtin_amdgcn_mfma_f32_16x16x32_f16(al, Bh[s], acc[cs][s], 0, 0, 0);
            acc[cs][s] = __builtin_amdgcn_mfma_f32_16x16x32_f16(ah, Bl[s], acc[cs][s], 0, 0, 0);
            acc[cs][s] = __builtin_amdgcn_mfma_f32_16x16x32_f16(ah, Bh[s], acc[cs][s], 0, 0, 0);
          }
        }
      }
    }
  }
  // epilogue: bc1 + relu, write Tb[cls][site][co]
#pragma unroll
  for (int cs = 0; cs < 2; cs++)
#pragma unroll
    for (int s = 0; s < 2; s++) {
      int site = nB + s * 16 + ln;
      int co0 = coW + cs * 16 + quad * 4;
      float4 bv = *(const float4*)&bc1[co0];
      float4 g = make_float4(fmaxf(acc[cs][s][0] + bv.x, 0.f),
                             fmaxf(acc[cs][s][1] + bv.y, 0.f),
                             fmaxf(acc[cs][s][2] + bv.z, 0.f),
                             fmaxf(acc[cs][s][3] + bv.w, 0.f));
      *(float4*)&Tb[(cls * 2048 + site) * 128 + co0] = g;
    }
}

// ---------- out: read Tb, 1x1 conv to 3ch, splat ----------------------------
__global__ __launch_bounds__(256) void k_out(const float* __restrict__ TbG,
                                             const float* __restrict__ w3,
                                             const float* __restrict__ b3,
                                             float* __restrict__ xhat,
                                             const float* __restrict__ loss_acc,
                                             float* __restrict__ out_loss) {
  __shared__ float Tb[9][128];
  __shared__ float part[9][3][8];
  __shared__ float vals[9][3];
  int bj = blockIdx.x, bi = blockIdx.y, b = blockIdx.z;
  int s = bi * 8 + bj;
  int n = b * 64 + s;
  int tid = threadIdx.x;
  if (bj == 0 && bi == 0 && b == 0 && tid == 0)
    out_loss[0] = loss_acc[0] * 1.25f / 131072.0f;
  for (int i = tid; i < 1152; i += 256) {
    int cls = i >> 7, co = i & 127;
    Tb[cls][co] = TbG[(cls * 2048 + n) * 128 + co];
  }
  __syncthreads();
  if (tid < 216) {
    int cls = tid / 24, rem = tid - cls * 24;
    int cc = rem >> 3, seg = rem & 7;
    float ss = 0.f;
#pragma unroll
    for (int d = 0; d < 16; d++) ss = fmaf(w3[cc * 128 + seg * 16 + d], Tb[cls][seg * 16 + d], ss);
    part[cls][cc][seg] = ss;
  }
  __syncthreads();
  if (tid < 27) {
    int cls = tid / 3, cc = tid - cls * 3;
    float ss = b3[cc];
#pragma unroll
    for (int seg = 0; seg < 8; seg++) ss += part[cls][cc][seg];
    vals[cls][cc] = ss;
  }
  __syncthreads();
  for (int i = tid; i < 768; i += 256) {
    int cc = i >> 8, p = i & 255;
    int ry = p >> 4, rx = p & 15;
    int rcls = (ry == 0) ? 0 : ((ry == 15) ? 2 : 1);
    int ccls = (rx == 0) ? 0 : ((rx == 15) ? 2 : 1);
    xhat[((b * 3 + cc) * 128 + bi * 16 + ry) * 128 + bj * 16 + rx] =
        vals[rcls * 3 + ccls][cc];
  }
}

extern "C" void kernel_launch(void* const* d_in, const int* in_sizes, int n_in,
                              void* d_out, int out_size, void* d_ws, size_t ws_size,
                              hipStream_t stream) {
  const float* x   = (const float*)d_in[0];
  const float* w1  = (const float*)d_in[1];
  const float* b1  = (const float*)d_in[2];
  const float* w2  = (const float*)d_in[3];
  const float* b2  = (const float*)d_in[4];
  const float* wp  = (const float*)d_in[5];
  const float* pb  = (const float*)d_in[6];
  const float* cb  = (const float*)d_in[7];
  const float* wd  = (const float*)d_in[8];
  const float* db  = (const float*)d_in[9];
  const float* wc1 = (const float*)d_in[10];
  const float* bc1 = (const float*)d_in[11];
  const float* wc2 = (const float*)d_in[12];
  const float* bc2 = (const float*)d_in[13];
  float* out = (float*)d_out;
  float* ws  = (float*)d_ws;

  // workspace (float offsets):
  _Float16* h1h = (_Float16*)(ws);             // [0, 8388640) f16 plane (+tail)
  float* h2p    = ws + 16777280;               // 262144 (pooled)
  _Float16* WS  = (_Float16*)(ws + 20971584);  // 147456 fl (294912 f16)
  float* w1t    = ws + 21119040;               // 3456
  float* wpT    = ws + 21122496;               // 8192
  float* wdT    = ws + 21130688;               // 8192
  float* cbT    = ws + 21138880;               // 32768
  _Float16* Ahd = (_Float16*)(ws + 21171648);  // 204800 fl
  _Float16* Ald = (_Float16*)(ws + 21376448);  // 204800 fl -> end 21581248
  // overlays inside dead h1h region (valid after conv2):
  float* Tb      = ws;                         // [0, 2359296) 9*2048*128
  _Float16* Yh   = (_Float16*)(ws + 6553600);  // 131136 fl (2049*128 f16)
  _Float16* Yl   = (_Float16*)(ws + 6684736);  // 131136 fl
  float* lossacc = ws + 6815872;               // 1

  float* o_xhat = out;
  float* o_idx  = out + 1572864;
  float* o_loss = out + 1574912;
  float* o_ze   = out + 1574913;

  static bool s_attr_done = false;
  if (!s_attr_done) {
    (void)hipFuncSetAttribute((const void*)k_conv2,
                              hipFuncAttributeMaxDynamicSharedMemorySize, C2_LDSB);
    s_attr_done = true;
  }

  k_prep<<<dim3(153), 256, 0, stream>>>(w2, w1, wp, wd, wc1, cb,
                                        w1t, wpT, wdT, cbT, Ahd, Ald, WS, h1h);
  k_conv1<<<dim3(4, 16, 32), 256, 0, stream>>>(x, w1t, b1, h1h);
  k_conv2<<<dim3(256), 512, C2_LDSB, stream>>>(h1h, WS, b2, h2p);
  k_poolproj<<<dim3(128), 256, 0, stream>>>(h2p, wpT, pb, o_ze, lossacc);
  k_vqdproj<<<dim3(2048), 256, 0, stream>>>(o_ze, cbT, cb, wdT, db, o_idx, Yh, Yl, lossacc);
  k_dec<<<dim3(576), 256, 0, stream>>>(Yh, Yl, Ahd, Ald, bc1, Tb);
  k_out<<<dim3(8, 8, 32), 256, 0, stream>>>(Tb, wc2, bc2, o_xhat, lossacc, o_loss);
}

// Round 16
// 218.872 us; speedup vs baseline: 1.2380x; 1.0279x over previous
//
#include <hip/hip_runtime.h>
#include <math.h>

// ---------------------------------------------------------------------------
// VQVAE forward. v24: conv2 weight low-plane dropped (v14's term-drop applied
// to the A side). conv2 now computes Ah*Bh only -- weights f16-rounded, error
// ~3.4e-4 (2% of current absmax; VQ-discriminant ~1e-5 << gaps). MFMA/tap
// halves (4->2), weight staging halves (37.4 KB/step, LDS 108.2 KB), k_prep
// writes only the high plane (WS 73728 fl). dec keeps its full 3-term split.
// Everything else unchanged from v23 (best: 225.0 us).
// ---------------------------------------------------------------------------

typedef _Float16 f16x8 __attribute__((ext_vector_type(8)));
typedef float f32x4 __attribute__((ext_vector_type(4)));

#define H1N 16777216        // elements in h1 plane; zero tail after
#define YTAIL (2048 * 128)  // zero page in Yh/Yl for OOB shifts

// ---------- prep: A-agg (0..127), W-layout (128..143), cbT (144..151), misc -
__global__ __launch_bounds__(256) void k_prep(const float* __restrict__ w2,
                                              const float* __restrict__ w1,
                                              const float* __restrict__ wp,
                                              const float* __restrict__ wd,
                                              const float* __restrict__ wd1,
                                              const float* __restrict__ cb,
                                              float* __restrict__ w1t,
                                              float* __restrict__ wpT,
                                              float* __restrict__ wdT,
                                              float* __restrict__ cbT,
                                              _Float16* __restrict__ Ah,
                                              _Float16* __restrict__ Al,
                                              _Float16* __restrict__ WS,
                                              _Float16* __restrict__ h1h) {
  int bx = blockIdx.x, tid = threadIdx.x;
  if (bx < 128) {  // ---- A aggregation, block = co, lanes = ci (writes coalesced)
    __shared__ float wrow[1152];
    int co = bx;
    for (int i = tid; i < 1152; i += 256) wrow[i] = wd1[co * 1152 + i];
    __syncthreads();
    if (tid < 128) {
      int ci = tid;
      float w[9];
#pragma unroll
      for (int t = 0; t < 9; t++) w[t] = wrow[ci * 9 + t];
      float rx[3][5];
#pragma unroll
      for (int ky = 0; ky < 3; ky++) {
        float a0 = w[ky * 3 + 0], a1 = w[ky * 3 + 1], a2 = w[ky * 3 + 2];
        rx[ky][0] = a0; rx[ky][1] = a1 + a2; rx[ky][2] = a0 + a1 + a2;
        rx[ky][3] = a0 + a1; rx[ky][4] = a2;
      }
#pragma unroll
      for (int px = 0; px < 5; px++) {
        float s0 = rx[0][px], s1 = rx[1][px], s2 = rx[2][px];
        float ry[5];
        ry[0] = s0; ry[1] = s1 + s2; ry[2] = s0 + s1 + s2; ry[3] = s0 + s1; ry[4] = s2;
#pragma unroll
        for (int py = 0; py < 5; py++) {
          int pq = py * 5 + px;
          float v = ry[py];
          _Float16 h = (_Float16)v;
          int o = (pq * 128 + co) * 128 + ci;
          Ah[o] = h;
          Al[o] = (_Float16)(v - (float)h);
        }
      }
    }
    return;
  }
  if (bx < 144) {  // ---- W layout for conv2 staging: [tap][ci8g][co]x8 (high only)
    __shared__ float wst[9216];
    int co0 = (bx - 128) * 8;
    for (int i = tid; i < 9216; i += 256) wst[i] = w2[co0 * 1152 + i];
    __syncthreads();
    for (int i = tid; i < 9216; i += 256) {
      int co = i / 1152, r = i - co * 1152;
      int tap = r >> 7, ci = r & 127;
      float v = wst[co * 1152 + ci * 9 + tap];
      int og = ((tap * 16 + (ci >> 3)) * 128 + co0 + co) * 8 + (ci & 7);
      WS[og] = (_Float16)v;
    }
    return;
  }
  if (bx < 152) {  // ---- cbT tile transpose (64 k x 64 d), padded LDS
    __shared__ float cbs[64 * 65];
    int k0 = (bx - 144) * 64;
    for (int i = tid; i < 4096; i += 256) {
      int k = i >> 6, d = i & 63;
      cbs[k * 65 + d] = cb[(k0 + k) * 64 + d];
    }
    __syncthreads();
    for (int i = tid; i < 4096; i += 256) {
      int d = i >> 6, k = i & 63;
      cbT[d * 512 + k0 + k] = cbs[k * 65 + d];
    }
    return;
  }
  // ---- misc small transposes + h1 zero tail (writes lane-contiguous)
  for (int i = tid; i < 3456; i += 256) {  // w1t[t][co] = w1[co][t]
    int co = i & 127, t = i >> 7;
    w1t[t * 128 + co] = w1[co * 27 + t];
  }
  for (int i = tid; i < 8192; i += 256) {  // wpT[k][d] = wp[d][k]
    int d = i & 63, k = i >> 6;
    wpT[k * 64 + d] = wp[d * 128 + k];
  }
  for (int i = tid; i < 8192; i += 256) {  // wdT[d][co] = wd[co][d]
    int co = i & 127, d = i >> 7;
    wdT[d * 128 + co] = wd[co * 64 + d];
  }
  if (tid < 64) h1h[H1N + tid] = (_Float16)0.f;
}

// ---------- conv1: (32,3,128,128) -> h1 f16 [g][b][oh][ow][8ci] -------------
__global__ __launch_bounds__(256) void k_conv1(const float* __restrict__ x,
                                               const float* __restrict__ w1t,
                                               const float* __restrict__ b1,
                                               _Float16* __restrict__ h1h) {
  __shared__ float E[3][9][68];
  __shared__ float O[3][9][68];
  int co_t = blockIdx.x, oh_t = blockIdx.y, b = blockIdx.z;
  int oh0 = oh_t * 4;
  int tid = threadIdx.x;
  int wv = __builtin_amdgcn_readfirstlane(tid >> 6);
  int l = tid & 63;
  int coB = co_t * 32 + wv * 8;

  for (int idx = tid; idx < 1728; idx += 256) {
    int p = idx & 63, r = idx >> 6;
    int ci = r / 9, lr = r - ci * 9;
    int ih = 2 * oh0 - 1 + lr;
    float2 v = make_float2(0.f, 0.f);
    if ((unsigned)ih < 128u)
      v = *(const float2*)&x[((b * 3 + ci) * 128 + ih) * 128 + 2 * p];
    E[ci][lr][p] = v.x;
    O[ci][lr][p + 1] = v.y;
  }
  if (tid < 27) {
    int ci = tid / 9, lr = tid - ci * 9;
    O[ci][lr][0] = 0.f;
  }
  __syncthreads();

  int ohl = l >> 4, ow0 = (l & 15) * 4;
  int oh = oh0 + ohl;
  float4 acc[8];
#pragma unroll
  for (int q = 0; q < 8; q++) {
    float bv = b1[coB + q];
    acc[q] = make_float4(bv, bv, bv, bv);
  }
#pragma unroll
  for (int ci = 0; ci < 3; ci++) {
#pragma unroll
    for (int ky = 0; ky < 3; ky++) {
      int lr = 2 * ohl + ky;
      float4 ev = *(float4*)&E[ci][lr][ow0];
      float4 od = *(float4*)&O[ci][lr][ow0];
      float o4 = O[ci][lr][ow0 + 4];
      const float* wr = w1t + (ci * 9 + ky * 3) * 128 + coB;
#pragma unroll
      for (int q = 0; q < 8; q++) {
        float wa = wr[q], wb = wr[128 + q], wc = wr[256 + q];
        acc[q].x = fmaf(wa, od.x, acc[q].x);
        acc[q].x = fmaf(wb, ev.x, acc[q].x);
        acc[q].x = fmaf(wc, od.y, acc[q].x);
        acc[q].y = fmaf(wa, od.y, acc[q].y);
        acc[q].y = fmaf(wb, ev.y, acc[q].y);
        acc[q].y = fmaf(wc, od.z, acc[q].y);
        acc[q].z = fmaf(wa, od.z, acc[q].z);
        acc[q].z = fmaf(wb, ev.z, acc[q].z);
        acc[q].z = fmaf(wc, od.w, acc[q].z);
        acc[q].w = fmaf(wa, od.w, acc[q].w);
        acc[q].w = fmaf(wb, ev.w, acc[q].w);
        acc[q].w = fmaf(wc, o4,   acc[q].w);
      }
    }
  }
  int g = coB >> 3;
  int pbase = ((g * 32 + b) * 64 + oh) * 64;
#pragma unroll
  for (int oi = 0; oi < 4; oi++) {
    f16x8 hv;
#pragma unroll
    for (int q = 0; q < 8; q++)
      hv[q] = (_Float16)fmaxf(((const float*)&acc[q])[oi], 0.f);
    *(f16x8*)&h1h[(pbase + ow0 + oi) * 8] = hv;
  }
}

// ---------- conv2: fat-step all-LDS compute + fused 4x4 mean-pool ----------
// grid 256 = (b(32) x ohq(4) x cohalf(2)); block 512 = 8 waves. Weights:
// single (f16-rounded) plane -> 2 MFMA per tap-s, 37.4 KB/step staged.
// LDS: acts [0, 70720 B): chunk (g*17+r)*65 + (ph?33+u:u);
//      weights [70720, 108160 B): chunk (t*4+quad)*65 + co_in_64.
#define C2_ACHUNK 4420                          // 4*17*65
#define C2_WCHUNK 2340                          // 9*4*65 (single plane)
#define C2_WOFF (C2_ACHUNK * 8)                 // f16 offset of weight region
#define C2_LDSB ((C2_ACHUNK + C2_WCHUNK) * 16)  // 108160 bytes
#define C2_STEP 4194304                         // h1 advance per +32ci step
#define C2_WADV 4096                            // WS f16 advance per step

__global__ __launch_bounds__(512, 2) void k_conv2(const _Float16* __restrict__ h1h,
                                                  const _Float16* __restrict__ WS,
                                                  const float* __restrict__ b2,
                                                  float* __restrict__ h2p) {
  extern __shared__ _Float16 L[];
  int bx = blockIdx.x;
  int cohalf = bx & 1;
  int bq = bx >> 1;
  int b = bq >> 2, ohq = bq & 3;
  int oh0 = ohq * 8;
  int tid = threadIdx.x;
  int w = tid >> 6, l = tid & 63;
  int cw = w & 1, rw = w >> 1;
  int ln = l & 15, quad = l >> 4;

  // ---- act staging descriptors: 9 chunks/thread (tail tid<324) ----
  int cursA[9];
  int advA[9];
#pragma unroll
  for (int k = 0; k < 9; k++) {
    int c = (k < 8) ? (tid + k * 512) : (4096 + tid);
    if (c < C2_ACHUNK) {
      int q = c / 65, rem = c - q * 65;
      int ph = rem >= 33;
      int u = ph ? rem - 33 : rem;
      int r = q % 17, g = q / 17;
      int iw = ph ? 2 * u : 2 * u - 1;
      int ih = 2 * oh0 - 1 + r;
      bool ok = (ih >= 0) && (iw >= 0) && (iw < 64);
      cursA[k] = ok ? ((g * 32 + b) * 64 + ih) * 512 + iw * 8 : H1N;
      advA[k] = ok ? C2_STEP : 0;
    } else {
      cursA[k] = H1N;
      advA[k] = 0;
    }
  }
  // ---- weight staging descriptors: 5 chunks/thread (tail tid<292) ----
  int cursW[5];
#pragma unroll
  for (int k = 0; k < 5; k++) {
    int c = (k < 4) ? (tid + k * 512) : (2048 + tid);
    if (c < C2_WCHUNK) {
      int q65 = c / 65, u = c - q65 * 65;
      if (u > 63) u = 63;  // pad slot: stage harmless duplicate
      int t = q65 >> 2, ci8 = q65 & 3;
      cursW[k] = (t * 16 + ci8) * 1024 + (cohalf * 64 + u) * 8;
    } else {
      cursW[k] = 0;
    }
  }

  f32x4 acc[2][4] = {};  // [cs][s]
  for (int step = 0; step < 4; step++) {
    if (step) __syncthreads();  // prior compute done reading L
    // ---- stage acts(step) ----
#pragma unroll
    for (int k = 0; k < 8; k++) {
      __builtin_amdgcn_global_load_lds(
          (const __attribute__((address_space(1))) void*)(h1h + cursA[k]),
          (__attribute__((address_space(3))) void*)&L[(tid + k * 512) * 8],
          16, 0, 0);
      cursA[k] += advA[k];
    }
    if (tid < 324)
      __builtin_amdgcn_global_load_lds(
          (const __attribute__((address_space(1))) void*)(h1h + cursA[8]),
          (__attribute__((address_space(3))) void*)&L[(4096 + tid) * 8],
          16, 0, 0);
    cursA[8] += advA[8];
    // ---- stage weights(step): single plane ----
#pragma unroll
    for (int k = 0; k < 4; k++) {
      __builtin_amdgcn_global_load_lds(
          (const __attribute__((address_space(1))) void*)(WS + cursW[k]),
          (__attribute__((address_space(3))) void*)&L[C2_WOFF +
                                                     (tid + k * 512) * 8],
          16, 0, 0);
      cursW[k] += C2_WADV;
    }
    if (tid < 292)
      __builtin_amdgcn_global_load_lds(
          (const __attribute__((address_space(1))) void*)(WS + cursW[4]),
          (__attribute__((address_space(3))) void*)&L[C2_WOFF +
                                                     (2048 + tid) * 8],
          16, 0, 0);
    cursW[4] += C2_WADV;
    __syncthreads();  // drain: acts + weights resident

    // ---- compute: pure LDS + MFMA (72 MFMA/wave/step) ----
#pragma unroll
    for (int ky = 0; ky < 3; ky++) {
#pragma unroll
      for (int kx = 0; kx < 3; kx++) {
        int t = ky * 3 + kx;
        int wb = (t * 4 + quad) * 65 + cw * 32 + ln;
        f16x8 Ah0 = *(const f16x8*)&L[C2_WOFF + wb * 8];
        f16x8 Ah1 = *(const f16x8*)&L[C2_WOFF + (wb + 16) * 8];
#pragma unroll
        for (int s = 0; s < 4; s++) {
          int owl = (s & 1) * 16 + ln;
          int r = 4 * rw + 2 * (s >> 1) + ky;
          int abase = (quad * 17 + r) * 65;
          int uoff = (kx == 1) ? (33 + owl) : (owl + (kx == 2));
          f16x8 Bh = *(const f16x8*)&L[(abase + uoff) * 8];
          acc[0][s] = __builtin_amdgcn_mfma_f32_16x16x32_f16(Ah0, Bh, acc[0][s], 0, 0, 0);
          acc[1][s] = __builtin_amdgcn_mfma_f32_16x16x32_f16(Ah1, Bh, acc[1][s], 0, 0, 0);
        }
      }
    }
  }
  // ---- epilogue: fused 4x4 mean-pool ----
  __syncthreads();  // all waves done reading L; reuse act region as h2s
  float* h2s = (float*)L;  // [64co][8row][32col] = 65536 B < 70720 B
#pragma unroll
  for (int cs = 0; cs < 2; cs++)
#pragma unroll
    for (int s = 0; s < 4; s++) {
      int row = 2 * rw + (s >> 1);
      int col = (s & 1) * 16 + ln;
#pragma unroll
      for (int r2 = 0; r2 < 4; r2++) {
        int co64 = cw * 32 + cs * 16 + quad * 4 + r2;
        int co = cohalf * 64 + co64;
        h2s[(co64 * 8 + row) * 32 + col] = fmaxf(acc[cs][s][r2] + b2[co], 0.f);
      }
    }
  __syncthreads();
  // 1024 pool cells (64co x 2pr x 8pc); v19 poolproj's exact add order
  for (int c = tid; c < 1024; c += 512) {
    int co64 = c >> 4, rem = c & 15;
    int pr = rem >> 3, pc = rem & 7;
    const float* base = &h2s[(co64 * 8 + pr * 4) * 32 + pc * 4];
    float s = 0.f;
#pragma unroll
    for (int rr = 0; rr < 4; rr++) {
      s += base[rr * 32 + 0];
      s += base[rr * 32 + 1];
      s += base[rr * 32 + 2];
      s += base[rr * 32 + 3];
    }
    h2p[((b * 128 + cohalf * 64 + co64) * 8 + (2 * ohq + pr)) * 8 + pc] =
        s * 0.0625f;
  }
}

// ---------- proj(1x1,128->64) on pooled input; grid 128 (b x quarter) -------
__global__ __launch_bounds__(256) void k_poolproj(const float* __restrict__ h2p,
                                                  const float* __restrict__ wpT,
                                                  const float* __restrict__ pb,
                                                  float* __restrict__ z_e_out,
                                                  float* __restrict__ lossacc) {
  __shared__ float hp[128][16];
  __shared__ float Ws[128][64];
  int bx = blockIdx.x, tid = threadIdx.x;
  int b = bx >> 2, quarter = bx & 3;
  if (bx == 0 && tid == 0) lossacc[0] = 0.f;
  for (int i = tid; i < 8192; i += 256) Ws[i >> 6][i & 63] = wpT[i];
  for (int i = tid; i < 2048; i += 256) {
    int ci = i >> 4, pl = i & 15;
    hp[ci][pl] = h2p[(b * 128 + ci) * 64 + quarter * 16 + pl];
  }
  __syncthreads();
  int d = tid >> 2, s0 = (tid & 3) * 4;
  float4 acc = make_float4(0.f, 0.f, 0.f, 0.f);
  for (int k = 0; k < 128; k++) {
    float a = Ws[k][d];
    float4 h = *(float4*)&hp[k][s0];
    acc.x = fmaf(a, h.x, acc.x);
    acc.y = fmaf(a, h.y, acc.y);
    acc.z = fmaf(a, h.z, acc.z);
    acc.w = fmaf(a, h.w, acc.w);
  }
  float bv = pb[d];
  float4 r4 = make_float4(acc.x + bv, acc.y + bv, acc.z + bv, acc.w + bv);
  *(float4*)&z_e_out[(b * 64 + d) * 64 + quarter * 16 + s0] = r4;
}

// ---------- VQ argmin + loss + dproj; grid 2048 x 256 (4 waves) -------------
__global__ __launch_bounds__(256) void k_vqdproj(const float* __restrict__ z_e,
                                                 const float* __restrict__ cbT,
                                                 const float* __restrict__ cb,
                                                 const float* __restrict__ wdT,
                                                 const float* __restrict__ db,
                                                 float* __restrict__ idx_f,
                                                 _Float16* __restrict__ Yh,
                                                 _Float16* __restrict__ Yl,
                                                 float* __restrict__ loss_acc) {
  __shared__ float zs[64];
  __shared__ float zqv[64];
  __shared__ double wbst[4];
  __shared__ int wbi[4];
  int n = blockIdx.x, tid = threadIdx.x;
  int b = n >> 6, pi = n & 63;
  if (tid < 64) zs[tid] = z_e[(b * 64 + tid) * 64 + pi];
  if (n == 0 && tid < 64) {  // zero tail page for shifted reads in k_dec
    Yh[YTAIL + tid] = (_Float16)0.f;
    Yh[YTAIL + 64 + tid] = (_Float16)0.f;
    Yl[YTAIL + tid] = (_Float16)0.f;
    Yl[YTAIL + 64 + tid] = (_Float16)0.f;
  }
  __syncthreads();
  int w = tid >> 6, lane = tid & 63;
  double best = 1e300;
  int bi = 0;
#pragma unroll
  for (int j = 0; j < 2; j++) {
    int k = w * 128 + j * 64 + lane;
    double a0 = 0.0, a1 = 0.0, a2 = 0.0, a3 = 0.0;
#pragma unroll 4
    for (int d = 0; d < 64; d += 4) {
      double f0 = (double)zs[d] - (double)cbT[d * 512 + k];
      double f1 = (double)zs[d + 1] - (double)cbT[(d + 1) * 512 + k];
      double f2 = (double)zs[d + 2] - (double)cbT[(d + 2) * 512 + k];
      double f3 = (double)zs[d + 3] - (double)cbT[(d + 3) * 512 + k];
      a0 = fma(f0, f0, a0);
      a1 = fma(f1, f1, a1);
      a2 = fma(f2, f2, a2);
      a3 = fma(f3, f3, a3);
    }
    double acc = (a0 + a1) + (a2 + a3);
    if (acc < best) { best = acc; bi = k; }
  }
  for (int m = 1; m < 64; m <<= 1) {
    double ob = __shfl_xor(best, m, 64);
    int oi = __shfl_xor(bi, m, 64);
    if (ob < best || (ob == best && oi < bi)) { best = ob; bi = oi; }
  }
  if (lane == 0) { wbst[w] = best; wbi[w] = bi; }
  __syncthreads();
  best = wbst[0];
  bi = wbi[0];
#pragma unroll
  for (int q = 1; q < 4; q++) {
    double ob = wbst[q];
    int oi = wbi[q];
    if (ob < best || (ob == best && oi < bi)) { best = ob; bi = oi; }
  }
  if (tid < 64) {  // wave 0: loss + zq staging
    float zq_l = cb[bi * 64 + tid];
    float e = zq_l - zs[tid];
    float sq = e * e;
    for (int m = 1; m < 64; m <<= 1) sq += __shfl_xor(sq, m, 64);
    if (tid == 0) {
      idx_f[n] = (float)bi;
      atomicAdd(loss_acc, sq);
    }
    zqv[tid] = zq_l;
  }
  __syncthreads();
  if (tid < 128) {  // dproj: one co per thread
    float a = db[tid];
#pragma unroll 4
    for (int d = 0; d < 64; d++) a = fmaf(wdT[d * 128 + tid], zqv[d], a);
    float y = fmaxf(a, 0.f);
    _Float16 h = (_Float16)y;
    Yh[n * 128 + tid] = h;
    Yl[n * 128 + tid] = (_Float16)(y - (float)h);
  }
}

// ---------- dec: per-CLASS accumulated f16-split MFMA -> Tb[9][2048][128] ---
__global__ __launch_bounds__(256) void k_dec(const _Float16* __restrict__ Yh,
                                             const _Float16* __restrict__ Yl,
                                             const _Float16* __restrict__ Ah,
                                             const _Float16* __restrict__ Al,
                                             const float* __restrict__ bc1,
                                             float* __restrict__ Tb) {
  int bxx = blockIdx.x;
  int cls = bxx >> 6, n_t = bxx & 63;
  int rc = cls / 3, c3 = cls - rc * 3;
  const int rset[3][2] = {{0, 1}, {2, 2}, {3, 4}};
  const int rcnt[3] = {2, 1, 2};
  int w = threadIdx.x >> 6, l = threadIdx.x & 63;
  int ln = l & 15, quad = l >> 4;
  int coW = w * 32;
  int nB = n_t * 32;
  int kq = quad * 8;
  f32x4 acc[2][2] = {};
  for (int iy = 0; iy < rcnt[rc]; iy++) {
    int py = rset[rc][iy];
    int dy = (py == 0) ? -1 : ((py == 4) ? 1 : 0);
    for (int ix = 0; ix < rcnt[c3]; ix++) {
      int px = rset[c3][ix];
      int dx = (px == 0) ? -1 : ((px == 4) ? 1 : 0);
      int pq = py * 5 + px;
      int src[2];
#pragma unroll
      for (int s = 0; s < 2; s++) {
        int n = nB + s * 16 + ln;
        int bb = n >> 6, s6 = n & 63;
        int sy = (s6 >> 3) + dy, sx = (s6 & 7) + dx;
        bool ok = ((unsigned)sy < 8u) && ((unsigned)sx < 8u);
        src[s] = ok ? ((bb * 64 + sy * 8 + sx) * 128) : YTAIL;
      }
#pragma unroll 2
      for (int ci0 = 0; ci0 < 128; ci0 += 32) {
        const int wbase = (pq * 128 + coW + ln) * 128 + ci0 + kq;
        f16x8 Ah0 = *(const f16x8*)&Ah[wbase];
        f16x8 Al0 = *(const f16x8*)&Al[wbase];
        f16x8 Ah1 = *(const f16x8*)&Ah[wbase + 2048];
        f16x8 Al1 = *(const f16x8*)&Al[wbase + 2048];
        f16x8 Bh[2], Bl[2];
#pragma unroll
        for (int s = 0; s < 2; s++) {
          Bh[s] = *(const f16x8*)&Yh[src[s] + ci0 + kq];
          Bl[s] = *(const f16x8*)&Yl[src[s] + ci0 + kq];
        }
#pragma unroll
        for (int cs = 0; cs < 2; cs++) {
          f16x8 ah = cs ? Ah1 : Ah0;
          f16x8 al = cs ? Al1 : Al0;
#pragma unroll
          for (int s = 0; s < 2; s++) {
            acc[cs][s] = __builtin_amdgcn_mfma_f32_16x16x32_f16(al, Bh[s], acc[cs][s], 0, 0, 0);
            acc[cs][s] = __builtin_amdgcn_mfma_f32_16x16x32_f16(ah, Bl[s], acc[cs][s], 0, 0, 0);
            acc[cs][s] = __builtin_amdgcn_mfma_f32_16x16x32_f16(ah, Bh[s], acc[cs][s], 0, 0, 0);
          }
        }
      }
    }
  }
  // epilogue: bc1 + relu, write Tb[cls][site][co]
#pragma unroll
  for (int cs = 0; cs < 2; cs++)
#pragma unroll
    for (int s = 0; s < 2; s++) {
      int site = nB + s * 16 + ln;
      int co0 = coW + cs * 16 + quad * 4;
      float4 bv = *(const float4*)&bc1[co0];
      float4 g = make_float4(fmaxf(acc[cs][s][0] + bv.x, 0.f),
                             fmaxf(acc[cs][s][1] + bv.y, 0.f),
                             fmaxf(acc[cs][s][2] + bv.z, 0.f),
                             fmaxf(acc[cs][s][3] + bv.w, 0.f));
      *(float4*)&Tb[(cls * 2048 + site) * 128 + co0] = g;
    }
}

// ---------- out: read Tb, 1x1 conv to 3ch, splat ----------------------------
__global__ __launch_bounds__(256) void k_out(const float* __restrict__ TbG,
                                             const float* __restrict__ w3,
                                             const float* __restrict__ b3,
                                             float* __restrict__ xhat,
                                             const float* __restrict__ loss_acc,
                                             float* __restrict__ out_loss) {
  __shared__ float Tb[9][128];
  __shared__ float part[9][3][8];
  __shared__ float vals[9][3];
  int bj = blockIdx.x, bi = blockIdx.y, b = blockIdx.z;
  int s = bi * 8 + bj;
  int n = b * 64 + s;
  int tid = threadIdx.x;
  if (bj == 0 && bi == 0 && b == 0 && tid == 0)
    out_loss[0] = loss_acc[0] * 1.25f / 131072.0f;
  for (int i = tid; i < 1152; i += 256) {
    int cls = i >> 7, co = i & 127;
    Tb[cls][co] = TbG[(cls * 2048 + n) * 128 + co];
  }
  __syncthreads();
  if (tid < 216) {
    int cls = tid / 24, rem = tid - cls * 24;
    int cc = rem >> 3, seg = rem & 7;
    float ss = 0.f;
#pragma unroll
    for (int d = 0; d < 16; d++) ss = fmaf(w3[cc * 128 + seg * 16 + d], Tb[cls][seg * 16 + d], ss);
    part[cls][cc][seg] = ss;
  }
  __syncthreads();
  if (tid < 27) {
    int cls = tid / 3, cc = tid - cls * 3;
    float ss = b3[cc];
#pragma unroll
    for (int seg = 0; seg < 8; seg++) ss += part[cls][cc][seg];
    vals[cls][cc] = ss;
  }
  __syncthreads();
  for (int i = tid; i < 768; i += 256) {
    int cc = i >> 8, p = i & 255;
    int ry = p >> 4, rx = p & 15;
    int rcls = (ry == 0) ? 0 : ((ry == 15) ? 2 : 1);
    int ccls = (rx == 0) ? 0 : ((rx == 15) ? 2 : 1);
    xhat[((b * 3 + cc) * 128 + bi * 16 + ry) * 128 + bj * 16 + rx] =
        vals[rcls * 3 + ccls][cc];
  }
}

extern "C" void kernel_launch(void* const* d_in, const int* in_sizes, int n_in,
                              void* d_out, int out_size, void* d_ws, size_t ws_size,
                              hipStream_t stream) {
  const float* x   = (const float*)d_in[0];
  const float* w1  = (const float*)d_in[1];
  const float* b1  = (const float*)d_in[2];
  const float* w2  = (const float*)d_in[3];
  const float* b2  = (const float*)d_in[4];
  const float* wp  = (const float*)d_in[5];
  const float* pb  = (const float*)d_in[6];
  const float* cb  = (const float*)d_in[7];
  const float* wd  = (const float*)d_in[8];
  const float* db  = (const float*)d_in[9];
  const float* wc1 = (const float*)d_in[10];
  const float* bc1 = (const float*)d_in[11];
  const float* wc2 = (const float*)d_in[12];
  const float* bc2 = (const float*)d_in[13];
  float* out = (float*)d_out;
  float* ws  = (float*)d_ws;

  // workspace (float offsets):
  _Float16* h1h = (_Float16*)(ws);             // [0, 8388640) f16 plane (+tail)
  float* h2p    = ws + 16777280;               // 262144 (pooled)
  _Float16* WS  = (_Float16*)(ws + 20971584);  // 73728 fl (147456 f16, 1 plane)
  float* w1t    = ws + 21119040;               // 3456
  float* wpT    = ws + 21122496;               // 8192
  float* wdT    = ws + 21130688;               // 8192
  float* cbT    = ws + 21138880;               // 32768
  _Float16* Ahd = (_Float16*)(ws + 21171648);  // 204800 fl
  _Float16* Ald = (_Float16*)(ws + 21376448);  // 204800 fl -> end 21581248
  // overlays inside dead h1h region (valid after conv2):
  float* Tb      = ws;                         // [0, 2359296) 9*2048*128
  _Float16* Yh   = (_Float16*)(ws + 6553600);  // 131136 fl (2049*128 f16)
  _Float16* Yl   = (_Float16*)(ws + 6684736);  // 131136 fl
  float* lossacc = ws + 6815872;               // 1

  float* o_xhat = out;
  float* o_idx  = out + 1572864;
  float* o_loss = out + 1574912;
  float* o_ze   = out + 1574913;

  static bool s_attr_done = false;
  if (!s_attr_done) {
    (void)hipFuncSetAttribute((const void*)k_conv2,
                              hipFuncAttributeMaxDynamicSharedMemorySize, C2_LDSB);
    s_attr_done = true;
  }

  k_prep<<<dim3(153), 256, 0, stream>>>(w2, w1, wp, wd, wc1, cb,
                                        w1t, wpT, wdT, cbT, Ahd, Ald, WS, h1h);
  k_conv1<<<dim3(4, 16, 32), 256, 0, stream>>>(x, w1t, b1, h1h);
  k_conv2<<<dim3(256), 512, C2_LDSB, stream>>>(h1h, WS, b2, h2p);
  k_poolproj<<<dim3(128), 256, 0, stream>>>(h2p, wpT, pb, o_ze, lossacc);
  k_vqdproj<<<dim3(2048), 256, 0, stream>>>(o_ze, cbT, cb, wdT, db, o_idx, Yh, Yl, lossacc);
  k_dec<<<dim3(576), 256, 0, stream>>>(Yh, Yl, Ahd, Ald, bc1, Tb);
  k_out<<<dim3(8, 8, 32), 256, 0, stream>>>(Tb, wc2, bc2, o_xhat, lossacc, o_loss);
}

// Round 17
// 201.927 us; speedup vs baseline: 1.3419x; 1.0839x over previous
//
#include <hip/hip_runtime.h>
#include <math.h>

// ---------------------------------------------------------------------------
// VQVAE forward. v25: dec split terms dropped. v24 restored precision
// headroom (absmax 0.0156->0.0078); k_dec now computes the single-term
// Ah*Bh (A and Y f16-rounded; xhat error ~7e-5 << 0.0078). dec MFMA /3,
// Al/Yl never produced or read (prep drops Al plane, vqdproj drops Yl
// store). Everything else unchanged from v24 (best: 218.9 us).
// ---------------------------------------------------------------------------

typedef _Float16 f16x8 __attribute__((ext_vector_type(8)));
typedef float f32x4 __attribute__((ext_vector_type(4)));

#define H1N 16777216        // elements in h1 plane; zero tail after
#define YTAIL (2048 * 128)  // zero page in Yh for OOB shifts

// ---------- prep: A-agg (0..127), W-layout (128..143), cbT (144..151), misc -
__global__ __launch_bounds__(256) void k_prep(const float* __restrict__ w2,
                                              const float* __restrict__ w1,
                                              const float* __restrict__ wp,
                                              const float* __restrict__ wd,
                                              const float* __restrict__ wd1,
                                              const float* __restrict__ cb,
                                              float* __restrict__ w1t,
                                              float* __restrict__ wpT,
                                              float* __restrict__ wdT,
                                              float* __restrict__ cbT,
                                              _Float16* __restrict__ Ah,
                                              _Float16* __restrict__ WS,
                                              _Float16* __restrict__ h1h) {
  int bx = blockIdx.x, tid = threadIdx.x;
  if (bx < 128) {  // ---- A aggregation, block = co, lanes = ci (writes coalesced)
    __shared__ float wrow[1152];
    int co = bx;
    for (int i = tid; i < 1152; i += 256) wrow[i] = wd1[co * 1152 + i];
    __syncthreads();
    if (tid < 128) {
      int ci = tid;
      float w[9];
#pragma unroll
      for (int t = 0; t < 9; t++) w[t] = wrow[ci * 9 + t];
      float rx[3][5];
#pragma unroll
      for (int ky = 0; ky < 3; ky++) {
        float a0 = w[ky * 3 + 0], a1 = w[ky * 3 + 1], a2 = w[ky * 3 + 2];
        rx[ky][0] = a0; rx[ky][1] = a1 + a2; rx[ky][2] = a0 + a1 + a2;
        rx[ky][3] = a0 + a1; rx[ky][4] = a2;
      }
#pragma unroll
      for (int px = 0; px < 5; px++) {
        float s0 = rx[0][px], s1 = rx[1][px], s2 = rx[2][px];
        float ry[5];
        ry[0] = s0; ry[1] = s1 + s2; ry[2] = s0 + s1 + s2; ry[3] = s0 + s1; ry[4] = s2;
#pragma unroll
        for (int py = 0; py < 5; py++) {
          int pq = py * 5 + px;
          int o = (pq * 128 + co) * 128 + ci;
          Ah[o] = (_Float16)ry[py];
        }
      }
    }
    return;
  }
  if (bx < 144) {  // ---- W layout for conv2 staging: [tap][ci8g][co]x8 (high only)
    __shared__ float wst[9216];
    int co0 = (bx - 128) * 8;
    for (int i = tid; i < 9216; i += 256) wst[i] = w2[co0 * 1152 + i];
    __syncthreads();
    for (int i = tid; i < 9216; i += 256) {
      int co = i / 1152, r = i - co * 1152;
      int tap = r >> 7, ci = r & 127;
      float v = wst[co * 1152 + ci * 9 + tap];
      int og = ((tap * 16 + (ci >> 3)) * 128 + co0 + co) * 8 + (ci & 7);
      WS[og] = (_Float16)v;
    }
    return;
  }
  if (bx < 152) {  // ---- cbT tile transpose (64 k x 64 d), padded LDS
    __shared__ float cbs[64 * 65];
    int k0 = (bx - 144) * 64;
    for (int i = tid; i < 4096; i += 256) {
      int k = i >> 6, d = i & 63;
      cbs[k * 65 + d] = cb[(k0 + k) * 64 + d];
    }
    __syncthreads();
    for (int i = tid; i < 4096; i += 256) {
      int d = i >> 6, k = i & 63;
      cbT[d * 512 + k0 + k] = cbs[k * 65 + d];
    }
    return;
  }
  // ---- misc small transposes + h1 zero tail (writes lane-contiguous)
  for (int i = tid; i < 3456; i += 256) {  // w1t[t][co] = w1[co][t]
    int co = i & 127, t = i >> 7;
    w1t[t * 128 + co] = w1[co * 27 + t];
  }
  for (int i = tid; i < 8192; i += 256) {  // wpT[k][d] = wp[d][k]
    int d = i & 63, k = i >> 6;
    wpT[k * 64 + d] = wp[d * 128 + k];
  }
  for (int i = tid; i < 8192; i += 256) {  // wdT[d][co] = wd[co][d]
    int co = i & 127, d = i >> 7;
    wdT[d * 128 + co] = wd[co * 64 + d];
  }
  if (tid < 64) h1h[H1N + tid] = (_Float16)0.f;
}

// ---------- conv1: (32,3,128,128) -> h1 f16 [g][b][oh][ow][8ci] -------------
__global__ __launch_bounds__(256) void k_conv1(const float* __restrict__ x,
                                               const float* __restrict__ w1t,
                                               const float* __restrict__ b1,
                                               _Float16* __restrict__ h1h) {
  __shared__ float E[3][9][68];
  __shared__ float O[3][9][68];
  int co_t = blockIdx.x, oh_t = blockIdx.y, b = blockIdx.z;
  int oh0 = oh_t * 4;
  int tid = threadIdx.x;
  int wv = __builtin_amdgcn_readfirstlane(tid >> 6);
  int l = tid & 63;
  int coB = co_t * 32 + wv * 8;

  for (int idx = tid; idx < 1728; idx += 256) {
    int p = idx & 63, r = idx >> 6;
    int ci = r / 9, lr = r - ci * 9;
    int ih = 2 * oh0 - 1 + lr;
    float2 v = make_float2(0.f, 0.f);
    if ((unsigned)ih < 128u)
      v = *(const float2*)&x[((b * 3 + ci) * 128 + ih) * 128 + 2 * p];
    E[ci][lr][p] = v.x;
    O[ci][lr][p + 1] = v.y;
  }
  if (tid < 27) {
    int ci = tid / 9, lr = tid - ci * 9;
    O[ci][lr][0] = 0.f;
  }
  __syncthreads();

  int ohl = l >> 4, ow0 = (l & 15) * 4;
  int oh = oh0 + ohl;
  float4 acc[8];
#pragma unroll
  for (int q = 0; q < 8; q++) {
    float bv = b1[coB + q];
    acc[q] = make_float4(bv, bv, bv, bv);
  }
#pragma unroll
  for (int ci = 0; ci < 3; ci++) {
#pragma unroll
    for (int ky = 0; ky < 3; ky++) {
      int lr = 2 * ohl + ky;
      float4 ev = *(float4*)&E[ci][lr][ow0];
      float4 od = *(float4*)&O[ci][lr][ow0];
      float o4 = O[ci][lr][ow0 + 4];
      const float* wr = w1t + (ci * 9 + ky * 3) * 128 + coB;
#pragma unroll
      for (int q = 0; q < 8; q++) {
        float wa = wr[q], wb = wr[128 + q], wc = wr[256 + q];
        acc[q].x = fmaf(wa, od.x, acc[q].x);
        acc[q].x = fmaf(wb, ev.x, acc[q].x);
        acc[q].x = fmaf(wc, od.y, acc[q].x);
        acc[q].y = fmaf(wa, od.y, acc[q].y);
        acc[q].y = fmaf(wb, ev.y, acc[q].y);
        acc[q].y = fmaf(wc, od.z, acc[q].y);
        acc[q].z = fmaf(wa, od.z, acc[q].z);
        acc[q].z = fmaf(wb, ev.z, acc[q].z);
        acc[q].z = fmaf(wc, od.w, acc[q].z);
        acc[q].w = fmaf(wa, od.w, acc[q].w);
        acc[q].w = fmaf(wb, ev.w, acc[q].w);
        acc[q].w = fmaf(wc, o4,   acc[q].w);
      }
    }
  }
  int g = coB >> 3;
  int pbase = ((g * 32 + b) * 64 + oh) * 64;
#pragma unroll
  for (int oi = 0; oi < 4; oi++) {
    f16x8 hv;
#pragma unroll
    for (int q = 0; q < 8; q++)
      hv[q] = (_Float16)fmaxf(((const float*)&acc[q])[oi], 0.f);
    *(f16x8*)&h1h[(pbase + ow0 + oi) * 8] = hv;
  }
}

// ---------- conv2: fat-step all-LDS compute + fused 4x4 mean-pool ----------
#define C2_ACHUNK 4420                          // 4*17*65
#define C2_WCHUNK 2340                          // 9*4*65 (single plane)
#define C2_WOFF (C2_ACHUNK * 8)                 // f16 offset of weight region
#define C2_LDSB ((C2_ACHUNK + C2_WCHUNK) * 16)  // 108160 bytes
#define C2_STEP 4194304                         // h1 advance per +32ci step
#define C2_WADV 4096                            // WS f16 advance per step

__global__ __launch_bounds__(512, 2) void k_conv2(const _Float16* __restrict__ h1h,
                                                  const _Float16* __restrict__ WS,
                                                  const float* __restrict__ b2,
                                                  float* __restrict__ h2p) {
  extern __shared__ _Float16 L[];
  int bx = blockIdx.x;
  int cohalf = bx & 1;
  int bq = bx >> 1;
  int b = bq >> 2, ohq = bq & 3;
  int oh0 = ohq * 8;
  int tid = threadIdx.x;
  int w = tid >> 6, l = tid & 63;
  int cw = w & 1, rw = w >> 1;
  int ln = l & 15, quad = l >> 4;

  // ---- act staging descriptors: 9 chunks/thread (tail tid<324) ----
  int cursA[9];
  int advA[9];
#pragma unroll
  for (int k = 0; k < 9; k++) {
    int c = (k < 8) ? (tid + k * 512) : (4096 + tid);
    if (c < C2_ACHUNK) {
      int q = c / 65, rem = c - q * 65;
      int ph = rem >= 33;
      int u = ph ? rem - 33 : rem;
      int r = q % 17, g = q / 17;
      int iw = ph ? 2 * u : 2 * u - 1;
      int ih = 2 * oh0 - 1 + r;
      bool ok = (ih >= 0) && (iw >= 0) && (iw < 64);
      cursA[k] = ok ? ((g * 32 + b) * 64 + ih) * 512 + iw * 8 : H1N;
      advA[k] = ok ? C2_STEP : 0;
    } else {
      cursA[k] = H1N;
      advA[k] = 0;
    }
  }
  // ---- weight staging descriptors: 5 chunks/thread (tail tid<292) ----
  int cursW[5];
#pragma unroll
  for (int k = 0; k < 5; k++) {
    int c = (k < 4) ? (tid + k * 512) : (2048 + tid);
    if (c < C2_WCHUNK) {
      int q65 = c / 65, u = c - q65 * 65;
      if (u > 63) u = 63;  // pad slot: stage harmless duplicate
      int t = q65 >> 2, ci8 = q65 & 3;
      cursW[k] = (t * 16 + ci8) * 1024 + (cohalf * 64 + u) * 8;
    } else {
      cursW[k] = 0;
    }
  }

  f32x4 acc[2][4] = {};  // [cs][s]
  for (int step = 0; step < 4; step++) {
    if (step) __syncthreads();  // prior compute done reading L
    // ---- stage acts(step) ----
#pragma unroll
    for (int k = 0; k < 8; k++) {
      __builtin_amdgcn_global_load_lds(
          (const __attribute__((address_space(1))) void*)(h1h + cursA[k]),
          (__attribute__((address_space(3))) void*)&L[(tid + k * 512) * 8],
          16, 0, 0);
      cursA[k] += advA[k];
    }
    if (tid < 324)
      __builtin_amdgcn_global_load_lds(
          (const __attribute__((address_space(1))) void*)(h1h + cursA[8]),
          (__attribute__((address_space(3))) void*)&L[(4096 + tid) * 8],
          16, 0, 0);
    cursA[8] += advA[8];
    // ---- stage weights(step): single plane ----
#pragma unroll
    for (int k = 0; k < 4; k++) {
      __builtin_amdgcn_global_load_lds(
          (const __attribute__((address_space(1))) void*)(WS + cursW[k]),
          (__attribute__((address_space(3))) void*)&L[C2_WOFF +
                                                     (tid + k * 512) * 8],
          16, 0, 0);
      cursW[k] += C2_WADV;
    }
    if (tid < 292)
      __builtin_amdgcn_global_load_lds(
          (const __attribute__((address_space(1))) void*)(WS + cursW[4]),
          (__attribute__((address_space(3))) void*)&L[C2_WOFF +
                                                     (2048 + tid) * 8],
          16, 0, 0);
    cursW[4] += C2_WADV;
    __syncthreads();  // drain: acts + weights resident

    // ---- compute: pure LDS + MFMA (72 MFMA/wave/step) ----
#pragma unroll
    for (int ky = 0; ky < 3; ky++) {
#pragma unroll
      for (int kx = 0; kx < 3; kx++) {
        int t = ky * 3 + kx;
        int wb = (t * 4 + quad) * 65 + cw * 32 + ln;
        f16x8 Ah0 = *(const f16x8*)&L[C2_WOFF + wb * 8];
        f16x8 Ah1 = *(const f16x8*)&L[C2_WOFF + (wb + 16) * 8];
#pragma unroll
        for (int s = 0; s < 4; s++) {
          int owl = (s & 1) * 16 + ln;
          int r = 4 * rw + 2 * (s >> 1) + ky;
          int abase = (quad * 17 + r) * 65;
          int uoff = (kx == 1) ? (33 + owl) : (owl + (kx == 2));
          f16x8 Bh = *(const f16x8*)&L[(abase + uoff) * 8];
          acc[0][s] = __builtin_amdgcn_mfma_f32_16x16x32_f16(Ah0, Bh, acc[0][s], 0, 0, 0);
          acc[1][s] = __builtin_amdgcn_mfma_f32_16x16x32_f16(Ah1, Bh, acc[1][s], 0, 0, 0);
        }
      }
    }
  }
  // ---- epilogue: fused 4x4 mean-pool ----
  __syncthreads();  // all waves done reading L; reuse act region as h2s
  float* h2s = (float*)L;  // [64co][8row][32col] = 65536 B < 70720 B
#pragma unroll
  for (int cs = 0; cs < 2; cs++)
#pragma unroll
    for (int s = 0; s < 4; s++) {
      int row = 2 * rw + (s >> 1);
      int col = (s & 1) * 16 + ln;
#pragma unroll
      for (int r2 = 0; r2 < 4; r2++) {
        int co64 = cw * 32 + cs * 16 + quad * 4 + r2;
        int co = cohalf * 64 + co64;
        h2s[(co64 * 8 + row) * 32 + col] = fmaxf(acc[cs][s][r2] + b2[co], 0.f);
      }
    }
  __syncthreads();
  // 1024 pool cells (64co x 2pr x 8pc); v19 poolproj's exact add order
  for (int c = tid; c < 1024; c += 512) {
    int co64 = c >> 4, rem = c & 15;
    int pr = rem >> 3, pc = rem & 7;
    const float* base = &h2s[(co64 * 8 + pr * 4) * 32 + pc * 4];
    float s = 0.f;
#pragma unroll
    for (int rr = 0; rr < 4; rr++) {
      s += base[rr * 32 + 0];
      s += base[rr * 32 + 1];
      s += base[rr * 32 + 2];
      s += base[rr * 32 + 3];
    }
    h2p[((b * 128 + cohalf * 64 + co64) * 8 + (2 * ohq + pr)) * 8 + pc] =
        s * 0.0625f;
  }
}

// ---------- proj(1x1,128->64) on pooled input; grid 128 (b x quarter) -------
__global__ __launch_bounds__(256) void k_poolproj(const float* __restrict__ h2p,
                                                  const float* __restrict__ wpT,
                                                  const float* __restrict__ pb,
                                                  float* __restrict__ z_e_out,
                                                  float* __restrict__ lossacc) {
  __shared__ float hp[128][16];
  __shared__ float Ws[128][64];
  int bx = blockIdx.x, tid = threadIdx.x;
  int b = bx >> 2, quarter = bx & 3;
  if (bx == 0 && tid == 0) lossacc[0] = 0.f;
  for (int i = tid; i < 8192; i += 256) Ws[i >> 6][i & 63] = wpT[i];
  for (int i = tid; i < 2048; i += 256) {
    int ci = i >> 4, pl = i & 15;
    hp[ci][pl] = h2p[(b * 128 + ci) * 64 + quarter * 16 + pl];
  }
  __syncthreads();
  int d = tid >> 2, s0 = (tid & 3) * 4;
  float4 acc = make_float4(0.f, 0.f, 0.f, 0.f);
  for (int k = 0; k < 128; k++) {
    float a = Ws[k][d];
    float4 h = *(float4*)&hp[k][s0];
    acc.x = fmaf(a, h.x, acc.x);
    acc.y = fmaf(a, h.y, acc.y);
    acc.z = fmaf(a, h.z, acc.z);
    acc.w = fmaf(a, h.w, acc.w);
  }
  float bv = pb[d];
  float4 r4 = make_float4(acc.x + bv, acc.y + bv, acc.z + bv, acc.w + bv);
  *(float4*)&z_e_out[(b * 64 + d) * 64 + quarter * 16 + s0] = r4;
}

// ---------- VQ argmin + loss + dproj -> Yh f16; grid 2048 x 256 (4 waves) ---
__global__ __launch_bounds__(256) void k_vqdproj(const float* __restrict__ z_e,
                                                 const float* __restrict__ cbT,
                                                 const float* __restrict__ cb,
                                                 const float* __restrict__ wdT,
                                                 const float* __restrict__ db,
                                                 float* __restrict__ idx_f,
                                                 _Float16* __restrict__ Yh,
                                                 float* __restrict__ loss_acc) {
  __shared__ float zs[64];
  __shared__ float zqv[64];
  __shared__ double wbst[4];
  __shared__ int wbi[4];
  int n = blockIdx.x, tid = threadIdx.x;
  int b = n >> 6, pi = n & 63;
  if (tid < 64) zs[tid] = z_e[(b * 64 + tid) * 64 + pi];
  if (n == 0 && tid < 64) {  // zero tail page for shifted reads in k_dec
    Yh[YTAIL + tid] = (_Float16)0.f;
    Yh[YTAIL + 64 + tid] = (_Float16)0.f;
  }
  __syncthreads();
  int w = tid >> 6, lane = tid & 63;
  double best = 1e300;
  int bi = 0;
#pragma unroll
  for (int j = 0; j < 2; j++) {
    int k = w * 128 + j * 64 + lane;
    double a0 = 0.0, a1 = 0.0, a2 = 0.0, a3 = 0.0;
#pragma unroll 4
    for (int d = 0; d < 64; d += 4) {
      double f0 = (double)zs[d] - (double)cbT[d * 512 + k];
      double f1 = (double)zs[d + 1] - (double)cbT[(d + 1) * 512 + k];
      double f2 = (double)zs[d + 2] - (double)cbT[(d + 2) * 512 + k];
      double f3 = (double)zs[d + 3] - (double)cbT[(d + 3) * 512 + k];
      a0 = fma(f0, f0, a0);
      a1 = fma(f1, f1, a1);
      a2 = fma(f2, f2, a2);
      a3 = fma(f3, f3, a3);
    }
    double acc = (a0 + a1) + (a2 + a3);
    if (acc < best) { best = acc; bi = k; }
  }
  for (int m = 1; m < 64; m <<= 1) {
    double ob = __shfl_xor(best, m, 64);
    int oi = __shfl_xor(bi, m, 64);
    if (ob < best || (ob == best && oi < bi)) { best = ob; bi = oi; }
  }
  if (lane == 0) { wbst[w] = best; wbi[w] = bi; }
  __syncthreads();
  best = wbst[0];
  bi = wbi[0];
#pragma unroll
  for (int q = 1; q < 4; q++) {
    double ob = wbst[q];
    int oi = wbi[q];
    if (ob < best || (ob == best && oi < bi)) { best = ob; bi = oi; }
  }
  if (tid < 64) {  // wave 0: loss + zq staging
    float zq_l = cb[bi * 64 + tid];
    float e = zq_l - zs[tid];
    float sq = e * e;
    for (int m = 1; m < 64; m <<= 1) sq += __shfl_xor(sq, m, 64);
    if (tid == 0) {
      idx_f[n] = (float)bi;
      atomicAdd(loss_acc, sq);
    }
    zqv[tid] = zq_l;
  }
  __syncthreads();
  if (tid < 128) {  // dproj: one co per thread
    float a = db[tid];
#pragma unroll 4
    for (int d = 0; d < 64; d++) a = fmaf(wdT[d * 128 + tid], zqv[d], a);
    Yh[n * 128 + tid] = (_Float16)fmaxf(a, 0.f);
  }
}

// ---------- dec: per-CLASS single-term MFMA -> Tb[9][2048][128] -------------
// Tb[cls][n][co] = relu(bc1 + sum_{pq in cls} Ah_pq . Yh[shift_pq(n)]);
// A, Y f16-rounded (v25 term-drop; xhat error ~7e-5).
__global__ __launch_bounds__(256) void k_dec(const _Float16* __restrict__ Yh,
                                             const _Float16* __restrict__ Ah,
                                             const float* __restrict__ bc1,
                                             float* __restrict__ Tb) {
  int bxx = blockIdx.x;
  int cls = bxx >> 6, n_t = bxx & 63;
  int rc = cls / 3, c3 = cls - rc * 3;
  const int rset[3][2] = {{0, 1}, {2, 2}, {3, 4}};
  const int rcnt[3] = {2, 1, 2};
  int w = threadIdx.x >> 6, l = threadIdx.x & 63;
  int ln = l & 15, quad = l >> 4;
  int coW = w * 32;
  int nB = n_t * 32;
  int kq = quad * 8;
  f32x4 acc[2][2] = {};
  for (int iy = 0; iy < rcnt[rc]; iy++) {
    int py = rset[rc][iy];
    int dy = (py == 0) ? -1 : ((py == 4) ? 1 : 0);
    for (int ix = 0; ix < rcnt[c3]; ix++) {
      int px = rset[c3][ix];
      int dx = (px == 0) ? -1 : ((px == 4) ? 1 : 0);
      int pq = py * 5 + px;
      int src[2];
#pragma unroll
      for (int s = 0; s < 2; s++) {
        int n = nB + s * 16 + ln;
        int bb = n >> 6, s6 = n & 63;
        int sy = (s6 >> 3) + dy, sx = (s6 & 7) + dx;
        bool ok = ((unsigned)sy < 8u) && ((unsigned)sx < 8u);
        src[s] = ok ? ((bb * 64 + sy * 8 + sx) * 128) : YTAIL;
      }
#pragma unroll 2
      for (int ci0 = 0; ci0 < 128; ci0 += 32) {
        const int wbase = (pq * 128 + coW + ln) * 128 + ci0 + kq;
        f16x8 Ah0 = *(const f16x8*)&Ah[wbase];
        f16x8 Ah1 = *(const f16x8*)&Ah[wbase + 2048];
        f16x8 Bh[2];
#pragma unroll
        for (int s = 0; s < 2; s++)
          Bh[s] = *(const f16x8*)&Yh[src[s] + ci0 + kq];
#pragma unroll
        for (int cs = 0; cs < 2; cs++) {
          f16x8 ah = cs ? Ah1 : Ah0;
#pragma unroll
          for (int s = 0; s < 2; s++)
            acc[cs][s] = __builtin_amdgcn_mfma_f32_16x16x32_f16(ah, Bh[s], acc[cs][s], 0, 0, 0);
        }
      }
    }
  }
  // epilogue: bc1 + relu, write Tb[cls][site][co]
#pragma unroll
  for (int cs = 0; cs < 2; cs++)
#pragma unroll
    for (int s = 0; s < 2; s++) {
      int site = nB + s * 16 + ln;
      int co0 = coW + cs * 16 + quad * 4;
      float4 bv = *(const float4*)&bc1[co0];
      float4 g = make_float4(fmaxf(acc[cs][s][0] + bv.x, 0.f),
                             fmaxf(acc[cs][s][1] + bv.y, 0.f),
                             fmaxf(acc[cs][s][2] + bv.z, 0.f),
                             fmaxf(acc[cs][s][3] + bv.w, 0.f));
      *(float4*)&Tb[(cls * 2048 + site) * 128 + co0] = g;
    }
}

// ---------- out: read Tb, 1x1 conv to 3ch, splat ----------------------------
__global__ __launch_bounds__(256) void k_out(const float* __restrict__ TbG,
                                             const float* __restrict__ w3,
                                             const float* __restrict__ b3,
                                             float* __restrict__ xhat,
                                             const float* __restrict__ loss_acc,
                                             float* __restrict__ out_loss) {
  __shared__ float Tb[9][128];
  __shared__ float part[9][3][8];
  __shared__ float vals[9][3];
  int bj = blockIdx.x, bi = blockIdx.y, b = blockIdx.z;
  int s = bi * 8 + bj;
  int n = b * 64 + s;
  int tid = threadIdx.x;
  if (bj == 0 && bi == 0 && b == 0 && tid == 0)
    out_loss[0] = loss_acc[0] * 1.25f / 131072.0f;
  for (int i = tid; i < 1152; i += 256) {
    int cls = i >> 7, co = i & 127;
    Tb[cls][co] = TbG[(cls * 2048 + n) * 128 + co];
  }
  __syncthreads();
  if (tid < 216) {
    int cls = tid / 24, rem = tid - cls * 24;
    int cc = rem >> 3, seg = rem & 7;
    float ss = 0.f;
#pragma unroll
    for (int d = 0; d < 16; d++) ss = fmaf(w3[cc * 128 + seg * 16 + d], Tb[cls][seg * 16 + d], ss);
    part[cls][cc][seg] = ss;
  }
  __syncthreads();
  if (tid < 27) {
    int cls = tid / 3, cc = tid - cls * 3;
    float ss = b3[cc];
#pragma unroll
    for (int seg = 0; seg < 8; seg++) ss += part[cls][cc][seg];
    vals[cls][cc] = ss;
  }
  __syncthreads();
  for (int i = tid; i < 768; i += 256) {
    int cc = i >> 8, p = i & 255;
    int ry = p >> 4, rx = p & 15;
    int rcls = (ry == 0) ? 0 : ((ry == 15) ? 2 : 1);
    int ccls = (rx == 0) ? 0 : ((rx == 15) ? 2 : 1);
    xhat[((b * 3 + cc) * 128 + bi * 16 + ry) * 128 + bj * 16 + rx] =
        vals[rcls * 3 + ccls][cc];
  }
}

extern "C" void kernel_launch(void* const* d_in, const int* in_sizes, int n_in,
                              void* d_out, int out_size, void* d_ws, size_t ws_size,
                              hipStream_t stream) {
  const float* x   = (const float*)d_in[0];
  const float* w1  = (const float*)d_in[1];
  const float* b1  = (const float*)d_in[2];
  const float* w2  = (const float*)d_in[3];
  const float* b2  = (const float*)d_in[4];
  const float* wp  = (const float*)d_in[5];
  const float* pb  = (const float*)d_in[6];
  const float* cb  = (const float*)d_in[7];
  const float* wd  = (const float*)d_in[8];
  const float* db  = (const float*)d_in[9];
  const float* wc1 = (const float*)d_in[10];
  const float* bc1 = (const float*)d_in[11];
  const float* wc2 = (const float*)d_in[12];
  const float* bc2 = (const float*)d_in[13];
  float* out = (float*)d_out;
  float* ws  = (float*)d_ws;

  // workspace (float offsets):
  _Float16* h1h = (_Float16*)(ws);             // [0, 8388640) f16 plane (+tail)
  float* h2p    = ws + 16777280;               // 262144 (pooled)
  _Float16* WS  = (_Float16*)(ws + 20971584);  // 73728 fl (147456 f16, 1 plane)
  float* w1t    = ws + 21119040;               // 3456
  float* wpT    = ws + 21122496;               // 8192
  float* wdT    = ws + 21130688;               // 8192
  float* cbT    = ws + 21138880;               // 32768
  _Float16* Ahd = (_Float16*)(ws + 21171648);  // 204800 fl -> end 21376448
  // overlays inside dead h1h region (valid after conv2):
  float* Tb      = ws;                         // [0, 2359296) 9*2048*128
  _Float16* Yh   = (_Float16*)(ws + 6553600);  // 131136 fl (2049*128 f16)
  float* lossacc = ws + 6815872;               // 1

  float* o_xhat = out;
  float* o_idx  = out + 1572864;
  float* o_loss = out + 1574912;
  float* o_ze   = out + 1574913;

  static bool s_attr_done = false;
  if (!s_attr_done) {
    (void)hipFuncSetAttribute((const void*)k_conv2,
                              hipFuncAttributeMaxDynamicSharedMemorySize, C2_LDSB);
    s_attr_done = true;
  }

  k_prep<<<dim3(153), 256, 0, stream>>>(w2, w1, wp, wd, wc1, cb,
                                        w1t, wpT, wdT, cbT, Ahd, WS, h1h);
  k_conv1<<<dim3(4, 16, 32), 256, 0, stream>>>(x, w1t, b1, h1h);
  k_conv2<<<dim3(256), 512, C2_LDSB, stream>>>(h1h, WS, b2, h2p);
  k_poolproj<<<dim3(128), 256, 0, stream>>>(h2p, wpT, pb, o_ze, lossacc);
  k_vqdproj<<<dim3(2048), 256, 0, stream>>>(o_ze, cbT, cb, wdT, db, o_idx, Yh, lossacc);
  k_dec<<<dim3(576), 256, 0, stream>>>(Yh, Ahd, bc1, Tb);
  k_out<<<dim3(8, 8, 32), 256, 0, stream>>>(Tb, wc2, bc2, o_xhat, lossacc, o_loss);
}

// Round 18
// 199.536 us; speedup vs baseline: 1.3580x; 1.0120x over previous
//
#include <hip/hip_runtime.h>
#include <math.h>

// ---------------------------------------------------------------------------
// VQVAE forward. v26: conv1 -> MFMA. The 3ci 3x3 stride-2 conv is a
// 128co x 27k x 64px GEMM per (b, oh-row): im2col K=27 padded to 32, one
// 16x16x32 f16 MFMA per tile (8 MFMA/wave vs 864 scalar FMA/thread in v25).
// x f16-rounded (adds ~1e-3 to h1, comparable to its existing f16 store
// rounding; xhat ~1.4e-3 << 0.0078). Fragment convention identical to
// conv2/dec. w1 pre-padded by k_prep to w1A[128][32] f16.
// Everything else unchanged from v25 (best: 201.9 us).
// ---------------------------------------------------------------------------

typedef _Float16 f16x4 __attribute__((ext_vector_type(4)));
typedef _Float16 f16x8 __attribute__((ext_vector_type(8)));
typedef float f32x4 __attribute__((ext_vector_type(4)));

#define H1N 16777216        // elements in h1 plane; zero tail after
#define YTAIL (2048 * 128)  // zero page in Yh for OOB shifts

// ---------- prep: A-agg (0..127), W-layout (128..143), cbT (144..151), misc -
__global__ __launch_bounds__(256) void k_prep(const float* __restrict__ w2,
                                              const float* __restrict__ w1,
                                              const float* __restrict__ wp,
                                              const float* __restrict__ wd,
                                              const float* __restrict__ wd1,
                                              const float* __restrict__ cb,
                                              _Float16* __restrict__ w1A,
                                              float* __restrict__ wpT,
                                              float* __restrict__ wdT,
                                              float* __restrict__ cbT,
                                              _Float16* __restrict__ Ah,
                                              _Float16* __restrict__ WS,
                                              _Float16* __restrict__ h1h) {
  int bx = blockIdx.x, tid = threadIdx.x;
  if (bx < 128) {  // ---- A aggregation, block = co, lanes = ci (writes coalesced)
    __shared__ float wrow[1152];
    int co = bx;
    for (int i = tid; i < 1152; i += 256) wrow[i] = wd1[co * 1152 + i];
    __syncthreads();
    if (tid < 128) {
      int ci = tid;
      float w[9];
#pragma unroll
      for (int t = 0; t < 9; t++) w[t] = wrow[ci * 9 + t];
      float rx[3][5];
#pragma unroll
      for (int ky = 0; ky < 3; ky++) {
        float a0 = w[ky * 3 + 0], a1 = w[ky * 3 + 1], a2 = w[ky * 3 + 2];
        rx[ky][0] = a0; rx[ky][1] = a1 + a2; rx[ky][2] = a0 + a1 + a2;
        rx[ky][3] = a0 + a1; rx[ky][4] = a2;
      }
#pragma unroll
      for (int px = 0; px < 5; px++) {
        float s0 = rx[0][px], s1 = rx[1][px], s2 = rx[2][px];
        float ry[5];
        ry[0] = s0; ry[1] = s1 + s2; ry[2] = s0 + s1 + s2; ry[3] = s0 + s1; ry[4] = s2;
#pragma unroll
        for (int py = 0; py < 5; py++) {
          int pq = py * 5 + px;
          int o = (pq * 128 + co) * 128 + ci;
          Ah[o] = (_Float16)ry[py];
        }
      }
    }
    return;
  }
  if (bx < 144) {  // ---- W layout for conv2 staging: [tap][ci8g][co]x8 (high only)
    __shared__ float wst[9216];
    int co0 = (bx - 128) * 8;
    for (int i = tid; i < 9216; i += 256) wst[i] = w2[co0 * 1152 + i];
    __syncthreads();
    for (int i = tid; i < 9216; i += 256) {
      int co = i / 1152, r = i - co * 1152;
      int tap = r >> 7, ci = r & 127;
      float v = wst[co * 1152 + ci * 9 + tap];
      int og = ((tap * 16 + (ci >> 3)) * 128 + co0 + co) * 8 + (ci & 7);
      WS[og] = (_Float16)v;
    }
    return;
  }
  if (bx < 152) {  // ---- cbT tile transpose (64 k x 64 d), padded LDS
    __shared__ float cbs[64 * 65];
    int k0 = (bx - 144) * 64;
    for (int i = tid; i < 4096; i += 256) {
      int k = i >> 6, d = i & 63;
      cbs[k * 65 + d] = cb[(k0 + k) * 64 + d];
    }
    __syncthreads();
    for (int i = tid; i < 4096; i += 256) {
      int d = i >> 6, k = i & 63;
      cbT[d * 512 + k0 + k] = cbs[k * 65 + d];
    }
    return;
  }
  // ---- misc: w1A (k-padded f16), wpT, wdT, h1 zero tail
  for (int i = tid; i < 4096; i += 256) {  // w1A[co][k32], k 27..31 = 0
    int co = i >> 5, k = i & 31;
    w1A[i] = (k < 27) ? (_Float16)w1[co * 27 + k] : (_Float16)0.f;
  }
  for (int i = tid; i < 8192; i += 256) {  // wpT[k][d] = wp[d][k]
    int d = i & 63, k = i >> 6;
    wpT[k * 64 + d] = wp[d * 128 + k];
  }
  for (int i = tid; i < 8192; i += 256) {  // wdT[d][co] = wd[co][d]
    int co = i & 127, d = i >> 7;
    wdT[d * 128 + co] = wd[co * 64 + d];
  }
  if (tid < 64) h1h[H1N + tid] = (_Float16)0.f;
}

// ---------- conv1: MFMA im2col GEMM; grid (oh 64, b 32), block 256 ----------
// Per block: one output row (128co x 64px). xs[3ci][3r][132] f16 staged from
// x (pad col 0 = ix=-1; OOB rows zero). J[64px][40] im2col (k = ci*9+ky*3+kx,
// value xs[ci][ky][2*px+kx]; k>=27 zero). As[128co][40] from w1A. 4 waves:
// wave w -> co 32w..32w+31; 8 MFMA (2 co-frag x 4 px-tile). Epilogue: bias+
// relu -> Cs[64px][136] f16 -> coalesced f16x8 stores to h1 [g][b][oh][ow][8].
__global__ __launch_bounds__(256) void k_conv1(const float* __restrict__ x,
                                               const _Float16* __restrict__ w1A,
                                               const float* __restrict__ b1,
                                               _Float16* __restrict__ h1h) {
  __shared__ _Float16 xs[3][3][132];
  __shared__ _Float16 J[64 * 40];
  __shared__ _Float16 As[128 * 40];
  __shared__ _Float16 Cs[64 * 136];
  int oh = blockIdx.x, b = blockIdx.y;
  int tid = threadIdx.x;
  int w = tid >> 6, l = tid & 63;
  int ln = l & 15, quad = l >> 4;
  int coW = w * 32;
  int kq = quad * 8;

  // stage x rows (f16) + pads
  for (int i = tid; i < 1152; i += 256) {
    int ci = i / 384, rem = i - ci * 384;
    int r = rem >> 7, iw = rem & 127;
    int ih = 2 * oh - 1 + r;
    float v = ((unsigned)ih < 128u) ? x[((b * 3 + ci) * 128 + ih) * 128 + iw] : 0.f;
    xs[ci][r][1 + iw] = (_Float16)v;
  }
  if (tid < 9) {
    int ci = tid / 3, r = tid - ci * 3;
    xs[ci][r][0] = (_Float16)0.f;
  }
  // stage A
  for (int i = tid; i < 4096; i += 256) {
    int co = i >> 5, k = i & 31;
    As[co * 40 + k] = w1A[i];
  }
  __syncthreads();
  // build im2col J
  for (int i = tid; i < 2048; i += 256) {
    int px = i >> 5, k = i & 31;
    _Float16 v = (_Float16)0.f;
    if (k < 27) {
      int ci = k / 9, t = k - ci * 9;
      int ky = t / 3, kx = t - ky * 3;
      v = xs[ci][ky][2 * px + kx];
    }
    J[px * 40 + k] = v;
  }
  __syncthreads();
  // MFMA: acc[cs 2][pt 4]
  f32x4 acc[2][4] = {};
#pragma unroll
  for (int cs = 0; cs < 2; cs++) {
    f16x8 a = *(const f16x8*)&As[(coW + cs * 16 + ln) * 40 + kq];
#pragma unroll
    for (int pt = 0; pt < 4; pt++) {
      f16x8 bfr = *(const f16x8*)&J[(pt * 16 + ln) * 40 + kq];
      acc[cs][pt] = __builtin_amdgcn_mfma_f32_16x16x32_f16(a, bfr, acc[cs][pt], 0, 0, 0);
    }
  }
  // epilogue: bias + relu -> Cs[px][co]
#pragma unroll
  for (int cs = 0; cs < 2; cs++) {
    int co0 = coW + cs * 16 + quad * 4;
    float4 bv = *(const float4*)&b1[co0];
#pragma unroll
    for (int pt = 0; pt < 4; pt++) {
      int px = pt * 16 + ln;
      f16x4 v;
      v[0] = (_Float16)fmaxf(acc[cs][pt][0] + bv.x, 0.f);
      v[1] = (_Float16)fmaxf(acc[cs][pt][1] + bv.y, 0.f);
      v[2] = (_Float16)fmaxf(acc[cs][pt][2] + bv.z, 0.f);
      v[3] = (_Float16)fmaxf(acc[cs][pt][3] + bv.w, 0.f);
      *(f16x4*)&Cs[px * 136 + co0] = v;
    }
  }
  __syncthreads();
  // coalesced store: h1h[((g*32+b)*64+oh)*64 + px]*8
  for (int i = tid; i < 1024; i += 256) {
    int g = i >> 6, px = i & 63;
    f16x8 v = *(const f16x8*)&Cs[px * 136 + g * 8];
    *(f16x8*)&h1h[(((g * 32 + b) * 64 + oh) * 64 + px) * 8] = v;
  }
}

// ---------- conv2: fat-step all-LDS compute + fused 4x4 mean-pool ----------
#define C2_ACHUNK 4420                          // 4*17*65
#define C2_WCHUNK 2340                          // 9*4*65 (single plane)
#define C2_WOFF (C2_ACHUNK * 8)                 // f16 offset of weight region
#define C2_LDSB ((C2_ACHUNK + C2_WCHUNK) * 16)  // 108160 bytes
#define C2_STEP 4194304                         // h1 advance per +32ci step
#define C2_WADV 4096                            // WS f16 advance per step

__global__ __launch_bounds__(512, 2) void k_conv2(const _Float16* __restrict__ h1h,
                                                  const _Float16* __restrict__ WS,
                                                  const float* __restrict__ b2,
                                                  float* __restrict__ h2p) {
  extern __shared__ _Float16 L[];
  int bx = blockIdx.x;
  int cohalf = bx & 1;
  int bq = bx >> 1;
  int b = bq >> 2, ohq = bq & 3;
  int oh0 = ohq * 8;
  int tid = threadIdx.x;
  int w = tid >> 6, l = tid & 63;
  int cw = w & 1, rw = w >> 1;
  int ln = l & 15, quad = l >> 4;

  // ---- act staging descriptors: 9 chunks/thread (tail tid<324) ----
  int cursA[9];
  int advA[9];
#pragma unroll
  for (int k = 0; k < 9; k++) {
    int c = (k < 8) ? (tid + k * 512) : (4096 + tid);
    if (c < C2_ACHUNK) {
      int q = c / 65, rem = c - q * 65;
      int ph = rem >= 33;
      int u = ph ? rem - 33 : rem;
      int r = q % 17, g = q / 17;
      int iw = ph ? 2 * u : 2 * u - 1;
      int ih = 2 * oh0 - 1 + r;
      bool ok = (ih >= 0) && (iw >= 0) && (iw < 64);
      cursA[k] = ok ? ((g * 32 + b) * 64 + ih) * 512 + iw * 8 : H1N;
      advA[k] = ok ? C2_STEP : 0;
    } else {
      cursA[k] = H1N;
      advA[k] = 0;
    }
  }
  // ---- weight staging descriptors: 5 chunks/thread (tail tid<292) ----
  int cursW[5];
#pragma unroll
  for (int k = 0; k < 5; k++) {
    int c = (k < 4) ? (tid + k * 512) : (2048 + tid);
    if (c < C2_WCHUNK) {
      int q65 = c / 65, u = c - q65 * 65;
      if (u > 63) u = 63;  // pad slot: stage harmless duplicate
      int t = q65 >> 2, ci8 = q65 & 3;
      cursW[k] = (t * 16 + ci8) * 1024 + (cohalf * 64 + u) * 8;
    } else {
      cursW[k] = 0;
    }
  }

  f32x4 acc[2][4] = {};  // [cs][s]
  for (int step = 0; step < 4; step++) {
    if (step) __syncthreads();  // prior compute done reading L
    // ---- stage acts(step) ----
#pragma unroll
    for (int k = 0; k < 8; k++) {
      __builtin_amdgcn_global_load_lds(
          (const __attribute__((address_space(1))) void*)(h1h + cursA[k]),
          (__attribute__((address_space(3))) void*)&L[(tid + k * 512) * 8],
          16, 0, 0);
      cursA[k] += advA[k];
    }
    if (tid < 324)
      __builtin_amdgcn_global_load_lds(
          (const __attribute__((address_space(1))) void*)(h1h + cursA[8]),
          (__attribute__((address_space(3))) void*)&L[(4096 + tid) * 8],
          16, 0, 0);
    cursA[8] += advA[8];
    // ---- stage weights(step): single plane ----
#pragma unroll
    for (int k = 0; k < 4; k++) {
      __builtin_amdgcn_global_load_lds(
          (const __attribute__((address_space(1))) void*)(WS + cursW[k]),
          (__attribute__((address_space(3))) void*)&L[C2_WOFF +
                                                     (tid + k * 512) * 8],
          16, 0, 0);
      cursW[k] += C2_WADV;
    }
    if (tid < 292)
      __builtin_amdgcn_global_load_lds(
          (const __attribute__((address_space(1))) void*)(WS + cursW[4]),
          (__attribute__((address_space(3))) void*)&L[C2_WOFF +
                                                     (2048 + tid) * 8],
          16, 0, 0);
    cursW[4] += C2_WADV;
    __syncthreads();  // drain: acts + weights resident

    // ---- compute: pure LDS + MFMA (72 MFMA/wave/step) ----
#pragma unroll
    for (int ky = 0; ky < 3; ky++) {
#pragma unroll
      for (int kx = 0; kx < 3; kx++) {
        int t = ky * 3 + kx;
        int wb = (t * 4 + quad) * 65 + cw * 32 + ln;
        f16x8 Ah0 = *(const f16x8*)&L[C2_WOFF + wb * 8];
        f16x8 Ah1 = *(const f16x8*)&L[C2_WOFF + (wb + 16) * 8];
#pragma unroll
        for (int s = 0; s < 4; s++) {
          int owl = (s & 1) * 16 + ln;
          int r = 4 * rw + 2 * (s >> 1) + ky;
          int abase = (quad * 17 + r) * 65;
          int uoff = (kx == 1) ? (33 + owl) : (owl + (kx == 2));
          f16x8 Bh = *(const f16x8*)&L[(abase + uoff) * 8];
          acc[0][s] = __builtin_amdgcn_mfma_f32_16x16x32_f16(Ah0, Bh, acc[0][s], 0, 0, 0);
          acc[1][s] = __builtin_amdgcn_mfma_f32_16x16x32_f16(Ah1, Bh, acc[1][s], 0, 0, 0);
        }
      }
    }
  }
  // ---- epilogue: fused 4x4 mean-pool ----
  __syncthreads();  // all waves done reading L; reuse act region as h2s
  float* h2s = (float*)L;  // [64co][8row][32col] = 65536 B < 70720 B
#pragma unroll
  for (int cs = 0; cs < 2; cs++)
#pragma unroll
    for (int s = 0; s < 4; s++) {
      int row = 2 * rw + (s >> 1);
      int col = (s & 1) * 16 + ln;
#pragma unroll
      for (int r2 = 0; r2 < 4; r2++) {
        int co64 = cw * 32 + cs * 16 + quad * 4 + r2;
        int co = cohalf * 64 + co64;
        h2s[(co64 * 8 + row) * 32 + col] = fmaxf(acc[cs][s][r2] + b2[co], 0.f);
      }
    }
  __syncthreads();
  // 1024 pool cells (64co x 2pr x 8pc); v19 poolproj's exact add order
  for (int c = tid; c < 1024; c += 512) {
    int co64 = c >> 4, rem = c & 15;
    int pr = rem >> 3, pc = rem & 7;
    const float* base = &h2s[(co64 * 8 + pr * 4) * 32 + pc * 4];
    float s = 0.f;
#pragma unroll
    for (int rr = 0; rr < 4; rr++) {
      s += base[rr * 32 + 0];
      s += base[rr * 32 + 1];
      s += base[rr * 32 + 2];
      s += base[rr * 32 + 3];
    }
    h2p[((b * 128 + cohalf * 64 + co64) * 8 + (2 * ohq + pr)) * 8 + pc] =
        s * 0.0625f;
  }
}

// ---------- proj(1x1,128->64) on pooled input; grid 128 (b x quarter) -------
__global__ __launch_bounds__(256) void k_poolproj(const float* __restrict__ h2p,
                                                  const float* __restrict__ wpT,
                                                  const float* __restrict__ pb,
                                                  float* __restrict__ z_e_out,
                                                  float* __restrict__ lossacc) {
  __shared__ float hp[128][16];
  __shared__ float Ws[128][64];
  int bx = blockIdx.x, tid = threadIdx.x;
  int b = bx >> 2, quarter = bx & 3;
  if (bx == 0 && tid == 0) lossacc[0] = 0.f;
  for (int i = tid; i < 8192; i += 256) Ws[i >> 6][i & 63] = wpT[i];
  for (int i = tid; i < 2048; i += 256) {
    int ci = i >> 4, pl = i & 15;
    hp[ci][pl] = h2p[(b * 128 + ci) * 64 + quarter * 16 + pl];
  }
  __syncthreads();
  int d = tid >> 2, s0 = (tid & 3) * 4;
  float4 acc = make_float4(0.f, 0.f, 0.f, 0.f);
  for (int k = 0; k < 128; k++) {
    float a = Ws[k][d];
    float4 h = *(float4*)&hp[k][s0];
    acc.x = fmaf(a, h.x, acc.x);
    acc.y = fmaf(a, h.y, acc.y);
    acc.z = fmaf(a, h.z, acc.z);
    acc.w = fmaf(a, h.w, acc.w);
  }
  float bv = pb[d];
  float4 r4 = make_float4(acc.x + bv, acc.y + bv, acc.z + bv, acc.w + bv);
  *(float4*)&z_e_out[(b * 64 + d) * 64 + quarter * 16 + s0] = r4;
}

// ---------- VQ argmin + loss + dproj -> Yh f16; grid 2048 x 256 (4 waves) ---
__global__ __launch_bounds__(256) void k_vqdproj(const float* __restrict__ z_e,
                                                 const float* __restrict__ cbT,
                                                 const float* __restrict__ cb,
                                                 const float* __restrict__ wdT,
                                                 const float* __restrict__ db,
                                                 float* __restrict__ idx_f,
                                                 _Float16* __restrict__ Yh,
                                                 float* __restrict__ loss_acc) {
  __shared__ float zs[64];
  __shared__ float zqv[64];
  __shared__ double wbst[4];
  __shared__ int wbi[4];
  int n = blockIdx.x, tid = threadIdx.x;
  int b = n >> 6, pi = n & 63;
  if (tid < 64) zs[tid] = z_e[(b * 64 + tid) * 64 + pi];
  if (n == 0 && tid < 64) {  // zero tail page for shifted reads in k_dec
    Yh[YTAIL + tid] = (_Float16)0.f;
    Yh[YTAIL + 64 + tid] = (_Float16)0.f;
  }
  __syncthreads();
  int w = tid >> 6, lane = tid & 63;
  double best = 1e300;
  int bi = 0;
#pragma unroll
  for (int j = 0; j < 2; j++) {
    int k = w * 128 + j * 64 + lane;
    double a0 = 0.0, a1 = 0.0, a2 = 0.0, a3 = 0.0;
#pragma unroll 4
    for (int d = 0; d < 64; d += 4) {
      double f0 = (double)zs[d] - (double)cbT[d * 512 + k];
      double f1 = (double)zs[d + 1] - (double)cbT[(d + 1) * 512 + k];
      double f2 = (double)zs[d + 2] - (double)cbT[(d + 2) * 512 + k];
      double f3 = (double)zs[d + 3] - (double)cbT[(d + 3) * 512 + k];
      a0 = fma(f0, f0, a0);
      a1 = fma(f1, f1, a1);
      a2 = fma(f2, f2, a2);
      a3 = fma(f3, f3, a3);
    }
    double acc = (a0 + a1) + (a2 + a3);
    if (acc < best) { best = acc; bi = k; }
  }
  for (int m = 1; m < 64; m <<= 1) {
    double ob = __shfl_xor(best, m, 64);
    int oi = __shfl_xor(bi, m, 64);
    if (ob < best || (ob == best && oi < bi)) { best = ob; bi = oi; }
  }
  if (lane == 0) { wbst[w] = best; wbi[w] = bi; }
  __syncthreads();
  best = wbst[0];
  bi = wbi[0];
#pragma unroll
  for (int q = 1; q < 4; q++) {
    double ob = wbst[q];
    int oi = wbi[q];
    if (ob < best || (ob == best && oi < bi)) { best = ob; bi = oi; }
  }
  if (tid < 64) {  // wave 0: loss + zq staging
    float zq_l = cb[bi * 64 + tid];
    float e = zq_l - zs[tid];
    float sq = e * e;
    for (int m = 1; m < 64; m <<= 1) sq += __shfl_xor(sq, m, 64);
    if (tid == 0) {
      idx_f[n] = (float)bi;
      atomicAdd(loss_acc, sq);
    }
    zqv[tid] = zq_l;
  }
  __syncthreads();
  if (tid < 128) {  // dproj: one co per thread
    float a = db[tid];
#pragma unroll 4
    for (int d = 0; d < 64; d++) a = fmaf(wdT[d * 128 + tid], zqv[d], a);
    Yh[n * 128 + tid] = (_Float16)fmaxf(a, 0.f);
  }
}

// ---------- dec: per-CLASS single-term MFMA -> Tb[9][2048][128] -------------
__global__ __launch_bounds__(256) void k_dec(const _Float16* __restrict__ Yh,
                                             const _Float16* __restrict__ Ah,
                                             const float* __restrict__ bc1,
                                             float* __restrict__ Tb) {
  int bxx = blockIdx.x;
  int cls = bxx >> 6, n_t = bxx & 63;
  int rc = cls / 3, c3 = cls - rc * 3;
  const int rset[3][2] = {{0, 1}, {2, 2}, {3, 4}};
  const int rcnt[3] = {2, 1, 2};
  int w = threadIdx.x >> 6, l = threadIdx.x & 63;
  int ln = l & 15, quad = l >> 4;
  int coW = w * 32;
  int nB = n_t * 32;
  int kq = quad * 8;
  f32x4 acc[2][2] = {};
  for (int iy = 0; iy < rcnt[rc]; iy++) {
    int py = rset[rc][iy];
    int dy = (py == 0) ? -1 : ((py == 4) ? 1 : 0);
    for (int ix = 0; ix < rcnt[c3]; ix++) {
      int px = rset[c3][ix];
      int dx = (px == 0) ? -1 : ((px == 4) ? 1 : 0);
      int pq = py * 5 + px;
      int src[2];
#pragma unroll
      for (int s = 0; s < 2; s++) {
        int n = nB + s * 16 + ln;
        int bb = n >> 6, s6 = n & 63;
        int sy = (s6 >> 3) + dy, sx = (s6 & 7) + dx;
        bool ok = ((unsigned)sy < 8u) && ((unsigned)sx < 8u);
        src[s] = ok ? ((bb * 64 + sy * 8 + sx) * 128) : YTAIL;
      }
#pragma unroll 2
      for (int ci0 = 0; ci0 < 128; ci0 += 32) {
        const int wbase = (pq * 128 + coW + ln) * 128 + ci0 + kq;
        f16x8 Ah0 = *(const f16x8*)&Ah[wbase];
        f16x8 Ah1 = *(const f16x8*)&Ah[wbase + 2048];
        f16x8 Bh[2];
#pragma unroll
        for (int s = 0; s < 2; s++)
          Bh[s] = *(const f16x8*)&Yh[src[s] + ci0 + kq];
#pragma unroll
        for (int cs = 0; cs < 2; cs++) {
          f16x8 ah = cs ? Ah1 : Ah0;
#pragma unroll
          for (int s = 0; s < 2; s++)
            acc[cs][s] = __builtin_amdgcn_mfma_f32_16x16x32_f16(ah, Bh[s], acc[cs][s], 0, 0, 0);
        }
      }
    }
  }
  // epilogue: bc1 + relu, write Tb[cls][site][co]
#pragma unroll
  for (int cs = 0; cs < 2; cs++)
#pragma unroll
    for (int s = 0; s < 2; s++) {
      int site = nB + s * 16 + ln;
      int co0 = coW + cs * 16 + quad * 4;
      float4 bv = *(const float4*)&bc1[co0];
      float4 g = make_float4(fmaxf(acc[cs][s][0] + bv.x, 0.f),
                             fmaxf(acc[cs][s][1] + bv.y, 0.f),
                             fmaxf(acc[cs][s][2] + bv.z, 0.f),
                             fmaxf(acc[cs][s][3] + bv.w, 0.f));
      *(float4*)&Tb[(cls * 2048 + site) * 128 + co0] = g;
    }
}

// ---------- out: read Tb, 1x1 conv to 3ch, splat ----------------------------
__global__ __launch_bounds__(256) void k_out(const float* __restrict__ TbG,
                                             const float* __restrict__ w3,
                                             const float* __restrict__ b3,
                                             float* __restrict__ xhat,
                                             const float* __restrict__ loss_acc,
                                             float* __restrict__ out_loss) {
  __shared__ float Tb[9][128];
  __shared__ float part[9][3][8];
  __shared__ float vals[9][3];
  int bj = blockIdx.x, bi = blockIdx.y, b = blockIdx.z;
  int s = bi * 8 + bj;
  int n = b * 64 + s;
  int tid = threadIdx.x;
  if (bj == 0 && bi == 0 && b == 0 && tid == 0)
    out_loss[0] = loss_acc[0] * 1.25f / 131072.0f;
  for (int i = tid; i < 1152; i += 256) {
    int cls = i >> 7, co = i & 127;
    Tb[cls][co] = TbG[(cls * 2048 + n) * 128 + co];
  }
  __syncthreads();
  if (tid < 216) {
    int cls = tid / 24, rem = tid - cls * 24;
    int cc = rem >> 3, seg = rem & 7;
    float ss = 0.f;
#pragma unroll
    for (int d = 0; d < 16; d++) ss = fmaf(w3[cc * 128 + seg * 16 + d], Tb[cls][seg * 16 + d], ss);
    part[cls][cc][seg] = ss;
  }
  __syncthreads();
  if (tid < 27) {
    int cls = tid / 3, cc = tid - cls * 3;
    float ss = b3[cc];
#pragma unroll
    for (int seg = 0; seg < 8; seg++) ss += part[cls][cc][seg];
    vals[cls][cc] = ss;
  }
  __syncthreads();
  for (int i = tid; i < 768; i += 256) {
    int cc = i >> 8, p = i & 255;
    int ry = p >> 4, rx = p & 15;
    int rcls = (ry == 0) ? 0 : ((ry == 15) ? 2 : 1);
    int ccls = (rx == 0) ? 0 : ((rx == 15) ? 2 : 1);
    xhat[((b * 3 + cc) * 128 + bi * 16 + ry) * 128 + bj * 16 + rx] =
        vals[rcls * 3 + ccls][cc];
  }
}

extern "C" void kernel_launch(void* const* d_in, const int* in_sizes, int n_in,
                              void* d_out, int out_size, void* d_ws, size_t ws_size,
                              hipStream_t stream) {
  const float* x   = (const float*)d_in[0];
  const float* w1  = (const float*)d_in[1];
  const float* b1  = (const float*)d_in[2];
  const float* w2  = (const float*)d_in[3];
  const float* b2  = (const float*)d_in[4];
  const float* wp  = (const float*)d_in[5];
  const float* pb  = (const float*)d_in[6];
  const float* cb  = (const float*)d_in[7];
  const float* wd  = (const float*)d_in[8];
  const float* db  = (const float*)d_in[9];
  const float* wc1 = (const float*)d_in[10];
  const float* bc1 = (const float*)d_in[11];
  const float* wc2 = (const float*)d_in[12];
  const float* bc2 = (const float*)d_in[13];
  float* out = (float*)d_out;
  float* ws  = (float*)d_ws;

  // workspace (float offsets):
  _Float16* h1h = (_Float16*)(ws);             // [0, 8388640) f16 plane (+tail)
  float* h2p    = ws + 16777280;               // 262144 (pooled)
  _Float16* WS  = (_Float16*)(ws + 20971584);  // 73728 fl (147456 f16, 1 plane)
  _Float16* w1A = (_Float16*)(ws + 21119040);  // 2048 fl (4096 f16)
  float* wpT    = ws + 21122496;               // 8192
  float* wdT    = ws + 21130688;               // 8192
  float* cbT    = ws + 21138880;               // 32768
  _Float16* Ahd = (_Float16*)(ws + 21171648);  // 204800 fl -> end 21376448
  // overlays inside dead h1h region (valid after conv2):
  float* Tb      = ws;                         // [0, 2359296) 9*2048*128
  _Float16* Yh   = (_Float16*)(ws + 6553600);  // 131136 fl (2049*128 f16)
  float* lossacc = ws + 6815872;               // 1

  float* o_xhat = out;
  float* o_idx  = out + 1572864;
  float* o_loss = out + 1574912;
  float* o_ze   = out + 1574913;

  static bool s_attr_done = false;
  if (!s_attr_done) {
    (void)hipFuncSetAttribute((const void*)k_conv2,
                              hipFuncAttributeMaxDynamicSharedMemorySize, C2_LDSB);
    s_attr_done = true;
  }

  k_prep<<<dim3(153), 256, 0, stream>>>(w2, w1, wp, wd, wc1, cb,
                                        w1A, wpT, wdT, cbT, Ahd, WS, h1h);
  k_conv1<<<dim3(64, 32), 256, 0, stream>>>(x, w1A, b1, h1h);
  k_conv2<<<dim3(256), 512, C2_LDSB, stream>>>(h1h, WS, b2, h2p);
  k_poolproj<<<dim3(128), 256, 0, stream>>>(h2p, wpT, pb, o_ze, lossacc);
  k_vqdproj<<<dim3(2048), 256, 0, stream>>>(o_ze, cbT, cb, wdT, db, o_idx, Yh, lossacc);
  k_dec<<<dim3(576), 256, 0, stream>>>(Yh, Ahd, bc1, Tb);
  k_out<<<dim3(8, 8, 32), 256, 0, stream>>>(Tb, wc2, bc2, o_xhat, lossacc, o_loss);
}